// Round 7
// baseline (764.037 us; speedup 1.0000x reference)
//
#include <hip/hip_runtime.h>
#include <hip/hip_cooperative_groups.h>

namespace cg = cooperative_groups;

// Problem constants (match reference)
constexpr int U_N = 50000;
constexpr int V_N = 50000;
constexpr int E_N = 800000;   // == 64 * 12500
// dims: F=64, G=64, H=16; g: 144->128->64; f: 128->128->64

typedef float f32x4 __attribute__((ext_vector_type(4)));
typedef short bf16x8 __attribute__((ext_vector_type(8)));

__device__ __forceinline__ float relu(float x) { return fmaxf(x, 0.f); }

// round-to-nearest-even fp32 -> bf16 bits
__device__ __forceinline__ unsigned short f2bf(float f) {
    unsigned u = __float_as_uint(f);
    unsigned rounding = 0x7FFFu + ((u >> 16) & 1u);
    return (unsigned short)((u + rounding) >> 16);
}
__device__ __forceinline__ float bf2f(unsigned short b) {
    return __uint_as_float(((unsigned)b) << 16);
}

constexpr int NB_PROJ = (U_N + 63) / 64;     // 782
constexpr int ETB     = 256;                 // edges per block (4 tiles x 64)
constexpr int NB_EDGE = E_N / ETB;           // 3125
constexpr int COOP_NB = 1024;                // cooperative sort grid
constexpr int SCAN_NB = (U_N + 255) / 256;   // 196 scan blocks

// ---------------------------------------------------------------------------
// proj body: P[row0..row0+64][128] = X @ W (64x128), bf16 output
// ---------------------------------------------------------------------------
__device__ __forceinline__ void proj_body(const float* __restrict__ X,
                                          const float* __restrict__ W,
                                          unsigned short* __restrict__ P,
                                          int N, int row0,
                                          float* sW, float* sX)
{
    const int tid = threadIdx.x;

    for (int i = tid * 4; i < 64 * 128; i += 1024)
        *(float4*)&sW[i] = *(const float4*)&W[i];
    for (int i = tid * 4; i < 64 * 64; i += 1024) {
        int r = i >> 6, c = i & 63;
        int gr = row0 + r;
        float4 val = (gr < N) ? *(const float4*)&X[(size_t)gr * 64 + c]
                              : make_float4(0.f, 0.f, 0.f, 0.f);
        *(float4*)&sX[i] = val;
    }
    __syncthreads();

    const int cg_ = tid & 31, rg = tid >> 5;
    const int c0 = cg_ * 4, r0 = rg * 8;
    float acc[8][4];
#pragma unroll
    for (int i = 0; i < 8; ++i)
#pragma unroll
        for (int j = 0; j < 4; ++j) acc[i][j] = 0.f;

#pragma unroll 4
    for (int k = 0; k < 64; ++k) {
        float4 w = *(const float4*)&sW[k * 128 + c0];
#pragma unroll
        for (int i = 0; i < 8; ++i) {
            float x = sX[(r0 + i) * 64 + k];
            acc[i][0] += x * w.x; acc[i][1] += x * w.y;
            acc[i][2] += x * w.z; acc[i][3] += x * w.w;
        }
    }
#pragma unroll
    for (int i = 0; i < 8; ++i) {
        int gr = row0 + r0 + i;
        if (gr < N) {
            ushort4 o;
            o.x = f2bf(acc[i][0]); o.y = f2bf(acc[i][1]);
            o.z = f2bf(acc[i][2]); o.w = f2bf(acc[i][3]);
            *(ushort4*)&P[(size_t)gr * 128 + c0] = o;
        }
    }
}

// ---------------------------------------------------------------------------
// prep kernel: projU, projV (bf16); last block packs W2f + Wef fragments.
// ---------------------------------------------------------------------------
__global__ __launch_bounds__(256) void prep_kernel(
    const float* __restrict__ u, const float* __restrict__ v,
    const float* __restrict__ gw1, const float* __restrict__ gw2,
    unsigned short* __restrict__ Up, unsigned short* __restrict__ Vp,
    unsigned short* __restrict__ W2f, unsigned short* __restrict__ Wef)
{
    __shared__ float sW[64 * 128];
    __shared__ float sX[64 * 64];
    int b = blockIdx.x;

    if (b < NB_PROJ) {
        proj_body(u, gw1, Up, U_N, b * 64, sW, sX);
        return;
    }
    b -= NB_PROJ;
    if (b < NB_PROJ) {
        proj_body(v, gw1 + 64 * 128, Vp, V_N, b * 64, sW, sX);
        return;
    }
    // ---- weight packing ----
    const int tid = threadIdx.x;
    for (int t = tid; t < 4 * 4 * 64 * 8; t += 256) {   // W2f: 8192
        int j    = t & 7;
        int lane = (t >> 3) & 63;
        int nt   = (t >> 9) & 3;
        int ks   = t >> 11;
        int n = nt * 16 + (lane & 15);
        int k = ks * 32 + (lane >> 4) * 8 + j;
        W2f[t] = f2bf(gw2[k * 64 + n]);
    }
    const float* gw1e = gw1 + 128 * 128;   // 16 x 128
    for (int t = tid; t < 8 * 64 * 8; t += 256) {       // Wef: 4096
        int j    = t & 7;
        int lane = (t >> 3) & 63;
        int ct   = t >> 9;
        int c = ct * 16 + (lane & 15);
        int k = (lane >> 4) * 8 + j;
        Wef[t] = (k < 16) ? f2bf(gw1e[k * 128 + c]) : (unsigned short)0;
    }
}

// ---------------------------------------------------------------------------
// cooperative sort: histogram -> two-level exclusive scan -> permute+gather.
// counts must be zeroed on entry; becomes the cursor array.
// ---------------------------------------------------------------------------
__global__ __launch_bounds__(256, 4) void sort_coop(
    const int* __restrict__ idx_u, const int* __restrict__ idx_v,
    const float* __restrict__ ev,
    int* __restrict__ counts, int* __restrict__ bsums,
    unsigned int* __restrict__ iuv_s, unsigned short* __restrict__ evs)
{
    cg::grid_group grid = cg::this_grid();
    const int tid = threadIdx.x;
    const int gidx = blockIdx.x * 256 + tid;
    const int gstride = COOP_NB * 256;

    // phase 1: histogram
    for (int e = gidx; e < E_N; e += gstride)
        atomicAdd(&counts[idx_u[e]], 1);
    grid.sync();

    // phase 2a: block-local inclusive scan over 256 counts
    __shared__ int sScan[256];
    int cval = 0, excl = 0;
    if (blockIdx.x < SCAN_NB) {
        int i = blockIdx.x * 256 + tid;
        cval = (i < U_N) ? counts[i] : 0;
        sScan[tid] = cval;
        __syncthreads();
        for (int off = 1; off < 256; off <<= 1) {
            int val = (tid >= off) ? sScan[tid - off] : 0;
            __syncthreads();
            sScan[tid] += val;
            __syncthreads();
        }
        excl = sScan[tid] - cval;
        if (tid == 255) bsums[blockIdx.x] = sScan[255];
    }
    grid.sync();

    // phase 2b: block 0 scans the block sums (exclusive)
    if (blockIdx.x == 0) {
        int s = (tid < SCAN_NB) ? bsums[tid] : 0;
        sScan[tid] = s;
        __syncthreads();
        for (int off = 1; off < 256; off <<= 1) {
            int val = (tid >= off) ? sScan[tid - off] : 0;
            __syncthreads();
            sScan[tid] += val;
            __syncthreads();
        }
        bsums[tid] = sScan[tid] - s;
    }
    grid.sync();

    // phase 2c: write exclusive prefix (cursor) back to counts
    if (blockIdx.x < SCAN_NB) {
        int i = blockIdx.x * 256 + tid;
        if (i < U_N) counts[i] = excl + bsums[blockIdx.x];
    }
    grid.sync();

    // phase 3: permute + pre-gather (iuv packed, ev row -> bf16)
    for (int e = gidx; e < E_N; e += gstride) {
        int iu = idx_u[e];
        int iv = idx_v[e];
        int pos = atomicAdd(&counts[iu], 1);
        iuv_s[pos] = (unsigned)iu | ((unsigned)iv << 16);
        const float* src = &ev[(size_t)e * 16];
        unsigned short* dst = &evs[(size_t)pos * 16];
#pragma unroll
        for (int q = 0; q < 4; ++q) {
            float4 a = *(const float4*)&src[q * 4];
            ushort4 o;
            o.x = f2bf(a.x); o.y = f2bf(a.y); o.z = f2bf(a.z); o.w = f2bf(a.w);
            *(ushort4*)&dst[q * 4] = o;
        }
    }
}

// ---------------------------------------------------------------------------
// edge kernel: 256 sorted edges/block (4 tiles x 64), 4 waves, wave-local
// everything, ZERO block barriers (DS ops are in-order within a wave).
// Software pipeline: tile t+1's Vp/ev prefetched during tile t's compute.
// ---------------------------------------------------------------------------
__global__ __launch_bounds__(256, 5) void edge_kernel(
    const unsigned short* __restrict__ Up,   // 50000 x 128 bf16
    const unsigned short* __restrict__ Vp,   // 50000 x 128 bf16
    const unsigned short* __restrict__ evs,  // E x 16 bf16, sorted
    const unsigned int* __restrict__ iuv_s,  // E packed (iu | iv<<16), sorted
    const unsigned short* __restrict__ Wef,  // layer-1 A frags (We^T, K=32 pad)
    const float* __restrict__ gb1,
    const unsigned short* __restrict__ W2f,  // layer-2 B frags
    const float* __restrict__ gb2,
    float* __restrict__ agg)
{
    __shared__ unsigned short sH1[64 * 136];  // aliased as sH2 f32 [64][68]
    __shared__ int sIu[64];

    const int tid = threadIdx.x;
    const int wid = tid >> 6, lane = tid & 63;
    const int lo = lane & 15, hi = lane >> 4;

    // bijective XCD-chunked swizzle (NB_EDGE % 8 != 0 -> m204 formula)
    constexpr int Q = NB_EDGE / 8, R = NB_EDGE % 8;   // 390, 5
    const int bid = blockIdx.x;
    const int xcd = bid % 8, posi = bid / 8;
    const int b = (xcd < R) ? xcd * (Q + 1) + posi
                            : R * (Q + 1) + (xcd - R) * Q + posi;

    const int eb = b * ETB + wid * 16 + lo;   // this lane's edge, tile 0

    unsigned iuv[4];
#pragma unroll
    for (int t = 0; t < 4; ++t) iuv[t] = iuv_s[eb + t * 64];

    ushort4 vpv[2][8];
    bf16x8  bfr[2];

    // prefetch tile 0
    {
        int iv0 = (int)(iuv[0] >> 16);
#pragma unroll
        for (int ct = 0; ct < 8; ++ct)
            vpv[0][ct] = *(const ushort4*)&Vp[(size_t)iv0 * 128 + ct * 16 + hi * 4];
        bfr[0] = (hi < 2) ? *(const bf16x8*)&evs[(size_t)eb * 16 + hi * 8]
                          : (bf16x8)(short)0;
    }

    float* const sH2 = (float*)sH1;   // same wave-local byte range
    const int e_loc = wid * 16 + lo;

#pragma unroll
    for (int t = 0; t < 4; ++t) {
        const int cur = t & 1, nxt = cur ^ 1;
        const int iu = (int)(iuv[t] & 0xFFFFu);

        if (hi == 0) sIu[e_loc] = iu;   // wave-local; in-order DS

        // ---- prefetch tile t+1 (independent of this tile's compute) ----
        if (t < 3) {
            int ivn = (int)(iuv[t + 1] >> 16);
#pragma unroll
            for (int ct = 0; ct < 8; ++ct)
                vpv[nxt][ct] = *(const ushort4*)&Vp[(size_t)ivn * 128 + ct * 16 + hi * 4];
            bfr[nxt] = (hi < 2)
                ? *(const bf16x8*)&evs[(size_t)(eb + (t + 1) * 64) * 16 + hi * 8]
                : (bf16x8)(short)0;
        }

        // ---- layer 1 MFMA (transposed): D[c][edge] ----
        f32x4 acc[8];
#pragma unroll
        for (int ct = 0; ct < 8; ++ct) {
#pragma unroll
            for (int r2 = 0; r2 < 4; ++r2) acc[ct][r2] = 0.f;
            bf16x8 a = *(const bf16x8*)&Wef[(ct * 64 + lane) * 8];
            acc[ct] = __builtin_amdgcn_mfma_f32_16x16x32_bf16(a, bfr[cur], acc[ct], 0, 0, 0);
        }

        // ---- epilogue: h1 = relu(acc + b1 + Up[iu] + Vp[iv]) -> bf16 LDS ----
#pragma unroll
        for (int ct = 0; ct < 8; ++ct) {
            int c0 = ct * 16 + hi * 4;
            ushort4 uv = *(const ushort4*)&Up[(size_t)iu * 128 + c0];  // cache-hot (sorted)
            float4 b1 = *(const float4*)&gb1[c0];
            ushort4 vv = vpv[cur][ct];
            ushort4 h;
            h.x = f2bf(relu(acc[ct][0] + b1.x + bf2f(uv.x) + bf2f(vv.x)));
            h.y = f2bf(relu(acc[ct][1] + b1.y + bf2f(uv.y) + bf2f(vv.y)));
            h.z = f2bf(relu(acc[ct][2] + b1.z + bf2f(uv.z) + bf2f(vv.z)));
            h.w = f2bf(relu(acc[ct][3] + b1.w + bf2f(uv.w) + bf2f(vv.w)));
            *(ushort4*)&sH1[e_loc * 136 + c0] = h;
        }

        // ---- layer 2 MFMA: wave reads its OWN 16 rows of sH1 ----
        f32x4 accm[4];
#pragma unroll
        for (int nt = 0; nt < 4; ++nt)
#pragma unroll
            for (int r2 = 0; r2 < 4; ++r2) accm[nt][r2] = 0.f;

#pragma unroll
        for (int ks = 0; ks < 4; ++ks) {
            bf16x8 a = *(const bf16x8*)&sH1[e_loc * 136 + ks * 32 + hi * 8];
#pragma unroll
            for (int nt = 0; nt < 4; ++nt) {
                bf16x8 bb = *(const bf16x8*)&W2f[((ks * 4 + nt) * 64 + lane) * 8];
                accm[nt] = __builtin_amdgcn_mfma_f32_16x16x32_bf16(a, bb, accm[nt], 0, 0, 0);
            }
        }

        // ---- h2 -> sH2 (f32); same wave-local bytes, in-order DS ----
#pragma unroll
        for (int nt = 0; nt < 4; ++nt) {
            int col = nt * 16 + lo;
            float b2v = gb2[col];
            int erow = wid * 16 + hi * 4;
#pragma unroll
            for (int r2 = 0; r2 < 4; ++r2)
                sH2[(erow + r2) * 68 + col] = relu(accm[nt][r2] + b2v);
        }

        // ---- segmented reduction (col = lane, own wave's 16 edges) ----
        {
            const int c = lane;
            const int eq0 = wid * 16;
            int   iu_cur = sIu[eq0];
            float running = 0.f;
#pragma unroll
            for (int k = 0; k < 16; ++k) {
                int iu2 = sIu[eq0 + k];
                if (iu2 != iu_cur) {
                    atomicAdd(&agg[(size_t)iu_cur * 64 + c], running);
                    running = 0.f;
                    iu_cur = iu2;
                }
                running += sH2[(eq0 + k) * 68 + c];
            }
            atomicAdd(&agg[(size_t)iu_cur * 64 + c], running);
        }
    }
}

// ---------------------------------------------------------------------------
// node kernel: out = relu(relu([u, agg] @ fw1 + fb1) @ fw2 + fb2)
// ---------------------------------------------------------------------------
__global__ __launch_bounds__(256) void node_kernel(
    const float* __restrict__ u, const float* __restrict__ agg,
    const float* __restrict__ fw1, const float* __restrict__ fb1,
    const float* __restrict__ fw2, const float* __restrict__ fb2,
    float* __restrict__ out, int N)
{
    __shared__ float sX[64 * 128];  // 32 KB
    __shared__ float sY[64 * 132];  // 33 KB
    const int tid = threadIdx.x;
    const int row0 = blockIdx.x * 64;

    for (int i = tid * 4; i < 64 * 64; i += 1024) {
        int r = i >> 6, c = i & 63;
        int gr = row0 + r;
        float4 uu = (gr < N) ? *(const float4*)&u[(size_t)gr * 64 + c]
                             : make_float4(0.f, 0.f, 0.f, 0.f);
        float4 aa = (gr < N) ? *(const float4*)&agg[(size_t)gr * 64 + c]
                             : make_float4(0.f, 0.f, 0.f, 0.f);
        *(float4*)&sX[r * 128 + c] = uu;
        *(float4*)&sX[r * 128 + 64 + c] = aa;
    }
    __syncthreads();

    {
        const int cg_ = tid & 31, rg = tid >> 5;
        const int c0 = cg_ * 4, r0 = rg * 8;
        const float4 bsv = *(const float4*)&fb1[c0];
        float acc[8][4];
#pragma unroll
        for (int i = 0; i < 8; ++i) {
            acc[i][0] = bsv.x; acc[i][1] = bsv.y; acc[i][2] = bsv.z; acc[i][3] = bsv.w;
        }
#pragma unroll 4
        for (int k = 0; k < 128; ++k) {
            float4 w = *(const float4*)&fw1[k * 128 + c0];
#pragma unroll
            for (int i = 0; i < 8; ++i) {
                float x = sX[(r0 + i) * 128 + k];
                acc[i][0] += x * w.x; acc[i][1] += x * w.y;
                acc[i][2] += x * w.z; acc[i][3] += x * w.w;
            }
        }
#pragma unroll
        for (int i = 0; i < 8; ++i) {
            float4 h = make_float4(relu(acc[i][0]), relu(acc[i][1]),
                                   relu(acc[i][2]), relu(acc[i][3]));
            *(float4*)&sY[(r0 + i) * 132 + c0] = h;
        }
    }
    __syncthreads();

    {
        const int cg_ = tid & 15, rg = tid >> 4;
        const int c0 = cg_ * 4;
        const float4 bsv = *(const float4*)&fb2[c0];
        float acc[4][4];
#pragma unroll
        for (int i = 0; i < 4; ++i) {
            acc[i][0] = bsv.x; acc[i][1] = bsv.y; acc[i][2] = bsv.z; acc[i][3] = bsv.w;
        }
#pragma unroll 4
        for (int k = 0; k < 128; ++k) {
            float4 w = *(const float4*)&fw2[k * 64 + c0];
#pragma unroll
            for (int i = 0; i < 4; ++i) {
                float yv = sY[(rg * 4 + i) * 132 + k];
                acc[i][0] += yv * w.x; acc[i][1] += yv * w.y;
                acc[i][2] += yv * w.z; acc[i][3] += yv * w.w;
            }
        }
#pragma unroll
        for (int i = 0; i < 4; ++i) {
            int gr = row0 + rg * 4 + i;
            if (gr < N) {
                float4 o = make_float4(relu(acc[i][0]), relu(acc[i][1]),
                                       relu(acc[i][2]), relu(acc[i][3]));
                *(float4*)&out[(size_t)gr * 64 + c0] = o;
            }
        }
    }
}

// ---------------------------------------------------------------------------
extern "C" void kernel_launch(void* const* d_in, const int* in_sizes, int n_in,
                              void* d_out, int out_size, void* d_ws, size_t ws_size,
                              hipStream_t stream)
{
    const float* u   = (const float*)d_in[0];
    const float* v   = (const float*)d_in[1];
    const float* ev  = (const float*)d_in[2];
    const int*   eiv = (const int*)d_in[3];
    const int*   eiu = (const int*)d_in[4];
    const float* gw1 = (const float*)d_in[5];   // 144 x 128
    const float* gb1 = (const float*)d_in[6];   // 128
    const float* gw2 = (const float*)d_in[7];   // 128 x 64
    const float* gb2 = (const float*)d_in[8];   // 64
    const float* fw1 = (const float*)d_in[9];   // 128 x 128
    const float* fb1 = (const float*)d_in[10];  // 128
    const float* fw2 = (const float*)d_in[11];  // 128 x 64
    const float* fb2 = (const float*)d_in[12];  // 64
    float* out = (float*)d_out;

    // workspace layout (agg and counts adjacent -> single memset); ~67.3 MB
    unsigned short* Up     = (unsigned short*)d_ws;                 // 50000x128 bf16
    unsigned short* Vp     = Up + (size_t)U_N * 128;                // 50000x128 bf16
    unsigned short* evs    = Vp + (size_t)V_N * 128;                // E x 16 bf16
    float*          agg    = (float*)(evs + (size_t)E_N * 16);      // 50000x64 f32
    int*            counts = (int*)(agg + (size_t)U_N * 64);        // 50000 (= cursor)
    unsigned int*   iuv_s  = (unsigned int*)(counts + U_N);         // 800000
    unsigned short* W2f    = (unsigned short*)(iuv_s + E_N);        // 8192 bf16
    unsigned short* Wef    = W2f + 8192;                            // 4096 bf16
    int*            bsums  = (int*)(Wef + 4096);                    // 256 ints

    // one memset covers agg (zero init) + counts (hist init)
    hipMemsetAsync(agg, 0, ((size_t)U_N * 64 + U_N) * sizeof(float), stream);

    dim3 blk(256);
    prep_kernel<<<dim3(2 * NB_PROJ + 1), blk, 0, stream>>>(
        u, v, gw1, gw2, Up, Vp, W2f, Wef);

    void* cargs[] = {(void*)&eiu, (void*)&eiv, (void*)&ev, (void*)&counts,
                     (void*)&bsums, (void*)&iuv_s, (void*)&evs};
    hipLaunchCooperativeKernel((const void*)sort_coop, dim3(COOP_NB), blk,
                               cargs, 0, stream);

    edge_kernel<<<dim3(NB_EDGE), blk, 0, stream>>>(
        Up, Vp, evs, iuv_s, Wef, gb1, W2f, gb2, agg);
    node_kernel<<<dim3((U_N + 63) / 64), blk, 0, stream>>>(
        u, agg, fw1, fb1, fw2, fb2, out, U_N);
}

// Round 8
// 465.148 us; speedup vs baseline: 1.6426x; 1.6426x over previous
//
#include <hip/hip_runtime.h>

// Problem constants (match reference)
constexpr int U_N = 50000;
constexpr int V_N = 50000;
constexpr int E_N = 800000;   // == 64 * 12500
// dims: F=64, G=64, H=16; g: 144->128->64; f: 128->128->64

typedef float f32x4 __attribute__((ext_vector_type(4)));
typedef short bf16x8 __attribute__((ext_vector_type(8)));

__device__ __forceinline__ float relu(float x) { return fmaxf(x, 0.f); }

// round-to-nearest-even fp32 -> bf16 bits
__device__ __forceinline__ unsigned short f2bf(float f) {
    unsigned u = __float_as_uint(f);
    unsigned rounding = 0x7FFFu + ((u >> 16) & 1u);
    return (unsigned short)((u + rounding) >> 16);
}
__device__ __forceinline__ float bf2f(unsigned short b) {
    return __uint_as_float(((unsigned)b) << 16);
}

constexpr int NB_HIST = (E_N + 255) / 256;   // 3125
constexpr int NB_PROJ = (U_N + 63) / 64;     // 782
constexpr int ETB     = 256;                 // edges per block (4 tiles x 64)
constexpr int NB_EDGE = E_N / ETB;           // 3125

// ---------------------------------------------------------------------------
// proj body: P[row0..row0+64][128] = X @ W (64x128), bf16 output
// ---------------------------------------------------------------------------
__device__ __forceinline__ void proj_body(const float* __restrict__ X,
                                          const float* __restrict__ W,
                                          unsigned short* __restrict__ P,
                                          int N, int row0,
                                          float* sW, float* sX)
{
    const int tid = threadIdx.x;

    for (int i = tid * 4; i < 64 * 128; i += 1024)
        *(float4*)&sW[i] = *(const float4*)&W[i];
    for (int i = tid * 4; i < 64 * 64; i += 1024) {
        int r = i >> 6, c = i & 63;
        int gr = row0 + r;
        float4 val = (gr < N) ? *(const float4*)&X[(size_t)gr * 64 + c]
                              : make_float4(0.f, 0.f, 0.f, 0.f);
        *(float4*)&sX[i] = val;
    }
    __syncthreads();

    const int cg_ = tid & 31, rg = tid >> 5;
    const int c0 = cg_ * 4, r0 = rg * 8;
    float acc[8][4];
#pragma unroll
    for (int i = 0; i < 8; ++i)
#pragma unroll
        for (int j = 0; j < 4; ++j) acc[i][j] = 0.f;

#pragma unroll 4
    for (int k = 0; k < 64; ++k) {
        float4 w = *(const float4*)&sW[k * 128 + c0];
#pragma unroll
        for (int i = 0; i < 8; ++i) {
            float x = sX[(r0 + i) * 64 + k];
            acc[i][0] += x * w.x; acc[i][1] += x * w.y;
            acc[i][2] += x * w.z; acc[i][3] += x * w.w;
        }
    }
#pragma unroll
    for (int i = 0; i < 8; ++i) {
        int gr = row0 + r0 + i;
        if (gr < N) {
            ushort4 o;
            o.x = f2bf(acc[i][0]); o.y = f2bf(acc[i][1]);
            o.z = f2bf(acc[i][2]); o.w = f2bf(acc[i][3]);
            *(ushort4*)&P[(size_t)gr * 128 + c0] = o;
        }
    }
}

// ---------------------------------------------------------------------------
// prep kernel: [0,NB_HIST) histogram; then projU, projV (bf16); last block
// packs W2f (layer-2 B-frags) and Wef (layer-1 A-frags, K padded to 32).
// Independent phases run as independent blocks of ONE launch (no grid.sync).
// ---------------------------------------------------------------------------
__global__ __launch_bounds__(256) void prep_kernel(
    const int* __restrict__ idx_u, int* __restrict__ counts,
    const float* __restrict__ u, const float* __restrict__ v,
    const float* __restrict__ gw1, const float* __restrict__ gw2,
    unsigned short* __restrict__ Up, unsigned short* __restrict__ Vp,
    unsigned short* __restrict__ W2f, unsigned short* __restrict__ Wef)
{
    __shared__ float sW[64 * 128];
    __shared__ float sX[64 * 64];
    int b = blockIdx.x;

    if (b < NB_HIST) {
        int e = b * 256 + threadIdx.x;
        if (e < E_N) atomicAdd(&counts[idx_u[e]], 1);
        return;
    }
    b -= NB_HIST;
    if (b < NB_PROJ) {
        proj_body(u, gw1, Up, U_N, b * 64, sW, sX);
        return;
    }
    b -= NB_PROJ;
    if (b < NB_PROJ) {
        proj_body(v, gw1 + 64 * 128, Vp, V_N, b * 64, sW, sX);
        return;
    }
    // ---- weight packing ----
    const int tid = threadIdx.x;
    for (int t = tid; t < 4 * 4 * 64 * 8; t += 256) {   // W2f: 8192
        int j    = t & 7;
        int lane = (t >> 3) & 63;
        int nt   = (t >> 9) & 3;
        int ks   = t >> 11;
        int n = nt * 16 + (lane & 15);
        int k = ks * 32 + (lane >> 4) * 8 + j;
        W2f[t] = f2bf(gw2[k * 64 + n]);
    }
    const float* gw1e = gw1 + 128 * 128;   // 16 x 128
    for (int t = tid; t < 8 * 64 * 8; t += 256) {       // Wef: 4096
        int j    = t & 7;
        int lane = (t >> 3) & 63;
        int ct   = t >> 9;
        int c = ct * 16 + (lane & 15);
        int k = (lane >> 4) * 8 + j;
        Wef[t] = (k < 16) ? f2bf(gw1e[k * 128 + c]) : (unsigned short)0;
    }
}

// ---------------------------------------------------------------------------
// single block, 1024 threads: in-place exclusive scan of counts[0..U_N)
// ---------------------------------------------------------------------------
__global__ __launch_bounds__(1024) void scan_kernel(int* __restrict__ counts)
{
    __shared__ int sPart[1024];
    const int tid = threadIdx.x;
    constexpr int CH = 49;          // 1024*49 = 50176 >= 50000
    const int base = tid * CH;

    int sum = 0;
#pragma unroll
    for (int k = 0; k < CH; ++k) {
        int i = base + k;
        if (i < U_N) sum += counts[i];
    }
    sPart[tid] = sum;
    __syncthreads();
    for (int off = 1; off < 1024; off <<= 1) {
        int val = (tid >= off) ? sPart[tid - off] : 0;
        __syncthreads();
        sPart[tid] += val;
        __syncthreads();
    }
    int run = sPart[tid] - sum;     // exclusive prefix for this chunk
    for (int k = 0; k < CH; ++k) {
        int i = base + k;
        if (i < U_N) { int c = counts[i]; counts[i] = run; run += c; }
    }
}

// ---------------------------------------------------------------------------
// permute+gather: scatter edges into sorted order, pre-gathering everything
// the edge kernel needs: iuv packed indices + ev row as bf16.
// ---------------------------------------------------------------------------
__global__ __launch_bounds__(256) void permute_kernel(
    const int* __restrict__ idx_u, const int* __restrict__ idx_v,
    const float* __restrict__ ev, int* __restrict__ cursor,
    unsigned int* __restrict__ iuv_s, unsigned short* __restrict__ evs)
{
    int e = blockIdx.x * 256 + threadIdx.x;
    if (e >= E_N) return;
    int iu = idx_u[e];
    int iv = idx_v[e];
    int pos = atomicAdd(&cursor[iu], 1);
    iuv_s[pos] = (unsigned)iu | ((unsigned)iv << 16);

    // ev row fp32->bf16, coalesced read, scattered 32B write (L3-resident)
    const float* src = &ev[(size_t)e * 16];
    unsigned short* dst = &evs[(size_t)pos * 16];
#pragma unroll
    for (int q = 0; q < 4; ++q) {
        float4 a = *(const float4*)&src[q * 4];
        ushort4 o;
        o.x = f2bf(a.x); o.y = f2bf(a.y); o.z = f2bf(a.z); o.w = f2bf(a.w);
        *(ushort4*)&dst[q * 4] = o;
    }
}

// ---------------------------------------------------------------------------
// edge kernel: 256 sorted edges/block (4 tiles x 64), 4 waves, wave-local
// everything, ZERO block barriers (DS ops are in-order within a wave).
// Software pipeline: tile t+1's Vp/ev prefetched during tile t's compute.
// ---------------------------------------------------------------------------
__global__ __launch_bounds__(256, 5) void edge_kernel(
    const unsigned short* __restrict__ Up,   // 50000 x 128 bf16
    const unsigned short* __restrict__ Vp,   // 50000 x 128 bf16
    const unsigned short* __restrict__ evs,  // E x 16 bf16, sorted
    const unsigned int* __restrict__ iuv_s,  // E packed (iu | iv<<16), sorted
    const unsigned short* __restrict__ Wef,  // layer-1 A frags (We^T, K=32 pad)
    const float* __restrict__ gb1,
    const unsigned short* __restrict__ W2f,  // layer-2 B frags
    const float* __restrict__ gb2,
    float* __restrict__ agg)
{
    __shared__ unsigned short sH1[64 * 136];  // aliased as sH2 f32 [64][68]
    __shared__ int sIu[64];

    const int tid = threadIdx.x;
    const int wid = tid >> 6, lane = tid & 63;
    const int lo = lane & 15, hi = lane >> 4;

    // bijective XCD-chunked swizzle (NB_EDGE % 8 != 0 -> m204 formula)
    constexpr int Q = NB_EDGE / 8, R = NB_EDGE % 8;   // 390, 5
    const int bid = blockIdx.x;
    const int xcd = bid % 8, posi = bid / 8;
    const int b = (xcd < R) ? xcd * (Q + 1) + posi
                            : R * (Q + 1) + (xcd - R) * Q + posi;

    const int eb = b * ETB + wid * 16 + lo;   // this lane's edge, tile 0

    unsigned iuv[4];
#pragma unroll
    for (int t = 0; t < 4; ++t) iuv[t] = iuv_s[eb + t * 64];

    ushort4 vpv[2][8];
    bf16x8  bfr[2];

    // prefetch tile 0
    {
        int iv0 = (int)(iuv[0] >> 16);
#pragma unroll
        for (int ct = 0; ct < 8; ++ct)
            vpv[0][ct] = *(const ushort4*)&Vp[(size_t)iv0 * 128 + ct * 16 + hi * 4];
        bfr[0] = (hi < 2) ? *(const bf16x8*)&evs[(size_t)eb * 16 + hi * 8]
                          : (bf16x8)(short)0;
    }

    float* const sH2 = (float*)sH1;   // same wave-local byte range
    const int e_loc = wid * 16 + lo;

#pragma unroll
    for (int t = 0; t < 4; ++t) {
        const int cur = t & 1, nxt = cur ^ 1;
        const int iu = (int)(iuv[t] & 0xFFFFu);

        if (hi == 0) sIu[e_loc] = iu;   // wave-local; in-order DS

        // ---- prefetch tile t+1 (independent of this tile's compute) ----
        if (t < 3) {
            int ivn = (int)(iuv[t + 1] >> 16);
#pragma unroll
            for (int ct = 0; ct < 8; ++ct)
                vpv[nxt][ct] = *(const ushort4*)&Vp[(size_t)ivn * 128 + ct * 16 + hi * 4];
            bfr[nxt] = (hi < 2)
                ? *(const bf16x8*)&evs[(size_t)(eb + (t + 1) * 64) * 16 + hi * 8]
                : (bf16x8)(short)0;
        }

        // ---- layer 1 MFMA (transposed): D[c][edge] ----
        f32x4 acc[8];
#pragma unroll
        for (int ct = 0; ct < 8; ++ct) {
#pragma unroll
            for (int r2 = 0; r2 < 4; ++r2) acc[ct][r2] = 0.f;
            bf16x8 a = *(const bf16x8*)&Wef[(ct * 64 + lane) * 8];
            acc[ct] = __builtin_amdgcn_mfma_f32_16x16x32_bf16(a, bfr[cur], acc[ct], 0, 0, 0);
        }

        // ---- epilogue: h1 = relu(acc + b1 + Up[iu] + Vp[iv]) -> bf16 LDS ----
#pragma unroll
        for (int ct = 0; ct < 8; ++ct) {
            int c0 = ct * 16 + hi * 4;
            ushort4 uv = *(const ushort4*)&Up[(size_t)iu * 128 + c0];  // cache-hot (sorted)
            float4 b1 = *(const float4*)&gb1[c0];
            ushort4 vv = vpv[cur][ct];
            ushort4 h;
            h.x = f2bf(relu(acc[ct][0] + b1.x + bf2f(uv.x) + bf2f(vv.x)));
            h.y = f2bf(relu(acc[ct][1] + b1.y + bf2f(uv.y) + bf2f(vv.y)));
            h.z = f2bf(relu(acc[ct][2] + b1.z + bf2f(uv.z) + bf2f(vv.z)));
            h.w = f2bf(relu(acc[ct][3] + b1.w + bf2f(uv.w) + bf2f(vv.w)));
            *(ushort4*)&sH1[e_loc * 136 + c0] = h;
        }

        // ---- layer 2 MFMA: wave reads its OWN 16 rows of sH1 ----
        f32x4 accm[4];
#pragma unroll
        for (int nt = 0; nt < 4; ++nt)
#pragma unroll
            for (int r2 = 0; r2 < 4; ++r2) accm[nt][r2] = 0.f;

#pragma unroll
        for (int ks = 0; ks < 4; ++ks) {
            bf16x8 a = *(const bf16x8*)&sH1[e_loc * 136 + ks * 32 + hi * 8];
#pragma unroll
            for (int nt = 0; nt < 4; ++nt) {
                bf16x8 bb = *(const bf16x8*)&W2f[((ks * 4 + nt) * 64 + lane) * 8];
                accm[nt] = __builtin_amdgcn_mfma_f32_16x16x32_bf16(a, bb, accm[nt], 0, 0, 0);
            }
        }

        // ---- h2 -> sH2 (f32); same wave-local bytes, in-order DS ----
#pragma unroll
        for (int nt = 0; nt < 4; ++nt) {
            int col = nt * 16 + lo;
            float b2v = gb2[col];
            int erow = wid * 16 + hi * 4;
#pragma unroll
            for (int r2 = 0; r2 < 4; ++r2)
                sH2[(erow + r2) * 68 + col] = relu(accm[nt][r2] + b2v);
        }

        // ---- segmented reduction (col = lane, own wave's 16 edges) ----
        {
            const int c = lane;
            const int eq0 = wid * 16;
            int   iu_cur = sIu[eq0];
            float running = 0.f;
#pragma unroll
            for (int k = 0; k < 16; ++k) {
                int iu2 = sIu[eq0 + k];
                if (iu2 != iu_cur) {
                    atomicAdd(&agg[(size_t)iu_cur * 64 + c], running);
                    running = 0.f;
                    iu_cur = iu2;
                }
                running += sH2[(eq0 + k) * 68 + c];
            }
            atomicAdd(&agg[(size_t)iu_cur * 64 + c], running);
        }
    }
}

// ---------------------------------------------------------------------------
// node kernel: out = relu(relu([u, agg] @ fw1 + fb1) @ fw2 + fb2)
// ---------------------------------------------------------------------------
__global__ __launch_bounds__(256) void node_kernel(
    const float* __restrict__ u, const float* __restrict__ agg,
    const float* __restrict__ fw1, const float* __restrict__ fb1,
    const float* __restrict__ fw2, const float* __restrict__ fb2,
    float* __restrict__ out, int N)
{
    __shared__ float sX[64 * 128];  // 32 KB
    __shared__ float sY[64 * 132];  // 33 KB
    const int tid = threadIdx.x;
    const int row0 = blockIdx.x * 64;

    for (int i = tid * 4; i < 64 * 64; i += 1024) {
        int r = i >> 6, c = i & 63;
        int gr = row0 + r;
        float4 uu = (gr < N) ? *(const float4*)&u[(size_t)gr * 64 + c]
                             : make_float4(0.f, 0.f, 0.f, 0.f);
        float4 aa = (gr < N) ? *(const float4*)&agg[(size_t)gr * 64 + c]
                             : make_float4(0.f, 0.f, 0.f, 0.f);
        *(float4*)&sX[r * 128 + c] = uu;
        *(float4*)&sX[r * 128 + 64 + c] = aa;
    }
    __syncthreads();

    {
        const int cg_ = tid & 31, rg = tid >> 5;
        const int c0 = cg_ * 4, r0 = rg * 8;
        const float4 bsv = *(const float4*)&fb1[c0];
        float acc[8][4];
#pragma unroll
        for (int i = 0; i < 8; ++i) {
            acc[i][0] = bsv.x; acc[i][1] = bsv.y; acc[i][2] = bsv.z; acc[i][3] = bsv.w;
        }
#pragma unroll 4
        for (int k = 0; k < 128; ++k) {
            float4 w = *(const float4*)&fw1[k * 128 + c0];
#pragma unroll
            for (int i = 0; i < 8; ++i) {
                float x = sX[(r0 + i) * 128 + k];
                acc[i][0] += x * w.x; acc[i][1] += x * w.y;
                acc[i][2] += x * w.z; acc[i][3] += x * w.w;
            }
        }
#pragma unroll
        for (int i = 0; i < 8; ++i) {
            float4 h = make_float4(relu(acc[i][0]), relu(acc[i][1]),
                                   relu(acc[i][2]), relu(acc[i][3]));
            *(float4*)&sY[(r0 + i) * 132 + c0] = h;
        }
    }
    __syncthreads();

    {
        const int cg_ = tid & 15, rg = tid >> 4;
        const int c0 = cg_ * 4;
        const float4 bsv = *(const float4*)&fb2[c0];
        float acc[4][4];
#pragma unroll
        for (int i = 0; i < 4; ++i) {
            acc[i][0] = bsv.x; acc[i][1] = bsv.y; acc[i][2] = bsv.z; acc[i][3] = bsv.w;
        }
#pragma unroll 4
        for (int k = 0; k < 128; ++k) {
            float4 w = *(const float4*)&fw2[k * 64 + c0];
#pragma unroll
            for (int i = 0; i < 4; ++i) {
                float yv = sY[(rg * 4 + i) * 132 + k];
                acc[i][0] += yv * w.x; acc[i][1] += yv * w.y;
                acc[i][2] += yv * w.z; acc[i][3] += yv * w.w;
            }
        }
#pragma unroll
        for (int i = 0; i < 4; ++i) {
            int gr = row0 + rg * 4 + i;
            if (gr < N) {
                float4 o = make_float4(relu(acc[i][0]), relu(acc[i][1]),
                                       relu(acc[i][2]), relu(acc[i][3]));
                *(float4*)&out[(size_t)gr * 64 + c0] = o;
            }
        }
    }
}

// ---------------------------------------------------------------------------
extern "C" void kernel_launch(void* const* d_in, const int* in_sizes, int n_in,
                              void* d_out, int out_size, void* d_ws, size_t ws_size,
                              hipStream_t stream)
{
    const float* u   = (const float*)d_in[0];
    const float* v   = (const float*)d_in[1];
    const float* ev  = (const float*)d_in[2];
    const int*   eiv = (const int*)d_in[3];
    const int*   eiu = (const int*)d_in[4];
    const float* gw1 = (const float*)d_in[5];   // 144 x 128
    const float* gb1 = (const float*)d_in[6];   // 128
    const float* gw2 = (const float*)d_in[7];   // 128 x 64
    const float* gb2 = (const float*)d_in[8];   // 64
    const float* fw1 = (const float*)d_in[9];   // 128 x 128
    const float* fb1 = (const float*)d_in[10];  // 128
    const float* fw2 = (const float*)d_in[11];  // 128 x 64
    const float* fb2 = (const float*)d_in[12];  // 64
    float* out = (float*)d_out;

    // workspace layout (agg and counts adjacent -> single memset); ~67.4 MB
    unsigned short* Up     = (unsigned short*)d_ws;                 // 50000x128 bf16
    unsigned short* Vp     = Up + (size_t)U_N * 128;                // 50000x128 bf16
    unsigned short* evs    = Vp + (size_t)V_N * 128;                // E x 16 bf16
    float*          agg    = (float*)(evs + (size_t)E_N * 16);      // 50000x64 f32
    int*            counts = (int*)(agg + (size_t)U_N * 64);        // 50000 (= cursor)
    unsigned int*   iuv_s  = (unsigned int*)(counts + U_N);         // 800000
    unsigned short* W2f    = (unsigned short*)(iuv_s + E_N);        // 8192 bf16
    unsigned short* Wef    = W2f + 8192;                            // 4096 bf16

    // one memset covers agg (zero init) + counts (hist init)
    hipMemsetAsync(agg, 0, ((size_t)U_N * 64 + U_N) * sizeof(float), stream);

    dim3 blk(256);
    prep_kernel<<<dim3(NB_HIST + 2 * NB_PROJ + 1), blk, 0, stream>>>(
        eiu, counts, u, v, gw1, gw2, Up, Vp, W2f, Wef);
    scan_kernel<<<dim3(1), dim3(1024), 0, stream>>>(counts);
    permute_kernel<<<dim3(NB_HIST), blk, 0, stream>>>(
        eiu, eiv, ev, counts, iuv_s, evs);

    edge_kernel<<<dim3(NB_EDGE), blk, 0, stream>>>(
        Up, Vp, evs, iuv_s, Wef, gb1, W2f, gb2, agg);
    node_kernel<<<dim3((U_N + 63) / 64), blk, 0, stream>>>(
        u, agg, fw1, fb1, fw2, fb2, out, U_N);
}

// Round 9
// 367.229 us; speedup vs baseline: 2.0805x; 1.2666x over previous
//
#include <hip/hip_runtime.h>

// Problem constants (match reference)
constexpr int U_N = 50000;
constexpr int V_N = 50000;
constexpr int E_N = 800000;   // == 64 * 12500
// dims: F=64, G=64, H=16; g: 144->128->64; f: 128->128->64

typedef float f32x4 __attribute__((ext_vector_type(4)));
typedef short bf16x8 __attribute__((ext_vector_type(8)));

__device__ __forceinline__ float relu(float x) { return fmaxf(x, 0.f); }

// round-to-nearest-even fp32 -> bf16 bits
__device__ __forceinline__ unsigned short f2bf(float f) {
    unsigned u = __float_as_uint(f);
    unsigned rounding = 0x7FFFu + ((u >> 16) & 1u);
    return (unsigned short)((u + rounding) >> 16);
}
__device__ __forceinline__ float bf2f(unsigned short b) {
    return __uint_as_float(((unsigned)b) << 16);
}

constexpr int NB_HIST = (E_N + 255) / 256;   // 3125
constexpr int NB_PROJ = (U_N + 63) / 64;     // 782

// ---------------------------------------------------------------------------
// proj via MFMA: P[row0..row0+64][128] = bf16(X[.][64]) @ bf16(W[64][128]),
// f32 accumulate, bf16 out. Same fragment convention as edge layer-2
// (verified): A[row=lo][k=ks*32+hi*8+j], B frag-major in LDS, D row=hi*4+r,
// col=nt*16+lo. Per-nt local accumulator keeps VGPR pressure ~50.
// ---------------------------------------------------------------------------
__device__ __forceinline__ void proj_mfma(const float* __restrict__ X,
                                          const float* __restrict__ W,  // 64x128
                                          unsigned short* __restrict__ P,
                                          int N, int row0,
                                          unsigned short* sWf)
{
    const int tid = threadIdx.x;

    // stage W -> fragment-major bf16 LDS: sWf[((ks*8+nt)*64 + hi*16+lo)*8 + j]
    for (int idx = tid; idx < 64 * 128 / 4; idx += 256) {
        int k  = (idx * 4) >> 7;       // W row (K dim)
        int n0 = (idx * 4) & 127;      // W col
        float4 w = *(const float4*)&W[k * 128 + n0];
        int ks = k >> 5, hi = (k & 31) >> 3, j = k & 7;
        float wv[4] = {w.x, w.y, w.z, w.w};
#pragma unroll
        for (int q = 0; q < 4; ++q) {
            int n = n0 + q, nt = n >> 4, lo = n & 15;
            sWf[((ks * 8 + nt) * 64 + hi * 16 + lo) * 8 + j] = f2bf(wv[q]);
        }
    }
    __syncthreads();

    const int wid = tid >> 6, lane = tid & 63;
    const int lo = lane & 15, hi = lane >> 4;
    const int row = row0 + wid * 16 + lo;
    const int rl = (row < N) ? row : (N - 1);   // clamp loads; mask stores

    // A-frags for ks=0,1 straight from global f32
    bf16x8 a0, a1;
    {
        union { bf16x8 v; unsigned short s[8]; } ra, rb;
        float4 x0 = *(const float4*)&X[(size_t)rl * 64 + hi * 8];
        float4 x1 = *(const float4*)&X[(size_t)rl * 64 + hi * 8 + 4];
        ra.s[0] = f2bf(x0.x); ra.s[1] = f2bf(x0.y); ra.s[2] = f2bf(x0.z); ra.s[3] = f2bf(x0.w);
        ra.s[4] = f2bf(x1.x); ra.s[5] = f2bf(x1.y); ra.s[6] = f2bf(x1.z); ra.s[7] = f2bf(x1.w);
        float4 y0 = *(const float4*)&X[(size_t)rl * 64 + 32 + hi * 8];
        float4 y1 = *(const float4*)&X[(size_t)rl * 64 + 32 + hi * 8 + 4];
        rb.s[0] = f2bf(y0.x); rb.s[1] = f2bf(y0.y); rb.s[2] = f2bf(y0.z); rb.s[3] = f2bf(y0.w);
        rb.s[4] = f2bf(y1.x); rb.s[5] = f2bf(y1.y); rb.s[6] = f2bf(y1.z); rb.s[7] = f2bf(y1.w);
        a0 = ra.v; a1 = rb.v;
    }

    const int rbase = row0 + wid * 16 + hi * 4;
#pragma unroll
    for (int nt = 0; nt < 8; ++nt) {
        f32x4 acc;
#pragma unroll
        for (int r = 0; r < 4; ++r) acc[r] = 0.f;
        bf16x8 b0 = *(const bf16x8*)&sWf[((0 * 8 + nt) * 64 + lane) * 8];
        bf16x8 b1 = *(const bf16x8*)&sWf[((1 * 8 + nt) * 64 + lane) * 8];
        acc = __builtin_amdgcn_mfma_f32_16x16x32_bf16(a0, b0, acc, 0, 0, 0);
        acc = __builtin_amdgcn_mfma_f32_16x16x32_bf16(a1, b1, acc, 0, 0, 0);
#pragma unroll
        for (int r = 0; r < 4; ++r) {
            int gr = rbase + r;
            if (gr < N) P[(size_t)gr * 128 + nt * 16 + lo] = f2bf(acc[r]);
        }
    }
}

// ---------------------------------------------------------------------------
// prep kernel: projU (MFMA), projV (MFMA), weight-pack, histogram — all as
// independent blocks of ONE launch (no grid.sync).
// ---------------------------------------------------------------------------
__global__ __launch_bounds__(256) void prep_kernel(
    const int* __restrict__ idx_u, int* __restrict__ counts,
    const float* __restrict__ u, const float* __restrict__ v,
    const float* __restrict__ gw1, const float* __restrict__ gw2,
    unsigned short* __restrict__ Up, unsigned short* __restrict__ Vp,
    unsigned short* __restrict__ W2f, unsigned short* __restrict__ Wef)
{
    __shared__ unsigned short sWf[8192];   // 16 KB (proj branches only)
    int b = blockIdx.x;

    if (b < NB_PROJ) {
        proj_mfma(u, gw1, Up, U_N, b * 64, sWf);
        return;
    }
    b -= NB_PROJ;
    if (b < NB_PROJ) {
        proj_mfma(v, gw1 + 64 * 128, Vp, V_N, b * 64, sWf);
        return;
    }
    b -= NB_PROJ;
    if (b == 0) {
        // ---- weight packing ----
        const int tid = threadIdx.x;
        for (int t = tid; t < 4 * 4 * 64 * 8; t += 256) {   // W2f: 8192
            int j    = t & 7;
            int lane = (t >> 3) & 63;
            int nt   = (t >> 9) & 3;
            int ks   = t >> 11;
            int n = nt * 16 + (lane & 15);
            int k = ks * 32 + (lane >> 4) * 8 + j;
            W2f[t] = f2bf(gw2[k * 64 + n]);
        }
        const float* gw1e = gw1 + 128 * 128;   // 16 x 128
        for (int t = tid; t < 8 * 64 * 8; t += 256) {       // Wef: 4096
            int j    = t & 7;
            int lane = (t >> 3) & 63;
            int ct   = t >> 9;
            int c = ct * 16 + (lane & 15);
            int k = (lane >> 4) * 8 + j;
            Wef[t] = (k < 16) ? f2bf(gw1e[k * 128 + c]) : (unsigned short)0;
        }
        return;
    }
    b -= 1;
    // ---- histogram ----
    int e = b * 256 + threadIdx.x;
    if (e < E_N) atomicAdd(&counts[idx_u[e]], 1);
}

// ---------------------------------------------------------------------------
// single block, 1024 threads: in-place exclusive scan of counts[0..U_N)
// ---------------------------------------------------------------------------
__global__ __launch_bounds__(1024) void scan_kernel(int* __restrict__ counts)
{
    __shared__ int sPart[1024];
    const int tid = threadIdx.x;
    constexpr int CH = 49;          // 1024*49 = 50176 >= 50000
    const int base = tid * CH;

    int sum = 0;
#pragma unroll
    for (int k = 0; k < CH; ++k) {
        int i = base + k;
        if (i < U_N) sum += counts[i];
    }
    sPart[tid] = sum;
    __syncthreads();
    for (int off = 1; off < 1024; off <<= 1) {
        int val = (tid >= off) ? sPart[tid - off] : 0;
        __syncthreads();
        sPart[tid] += val;
        __syncthreads();
    }
    int run = sPart[tid] - sum;     // exclusive prefix for this chunk
    for (int k = 0; k < CH; ++k) {
        int i = base + k;
        if (i < U_N) { int c = counts[i]; counts[i] = run; run += c; }
    }
}

// ---------------------------------------------------------------------------
// permute+gather: scatter edges into sorted order, pre-gathering everything
// the edge kernel needs: iuv packed indices + ev row as bf16.
// ---------------------------------------------------------------------------
__global__ __launch_bounds__(256) void permute_kernel(
    const int* __restrict__ idx_u, const int* __restrict__ idx_v,
    const float* __restrict__ ev, int* __restrict__ cursor,
    unsigned int* __restrict__ iuv_s, unsigned short* __restrict__ evs)
{
    int e = blockIdx.x * 256 + threadIdx.x;
    if (e >= E_N) return;
    int iu = idx_u[e];
    int iv = idx_v[e];
    int pos = atomicAdd(&cursor[iu], 1);
    iuv_s[pos] = (unsigned)iu | ((unsigned)iv << 16);

    // ev row fp32->bf16, coalesced read, scattered 32B write (L3-resident)
    const float* src = &ev[(size_t)e * 16];
    unsigned short* dst = &evs[(size_t)pos * 16];
#pragma unroll
    for (int q = 0; q < 4; ++q) {
        float4 a = *(const float4*)&src[q * 4];
        ushort4 o;
        o.x = f2bf(a.x); o.y = f2bf(a.y); o.z = f2bf(a.z); o.w = f2bf(a.w);
        *(ushort4*)&dst[q * 4] = o;
    }
}

// ---------------------------------------------------------------------------
// edge kernel over SORTED pre-gathered edges (exact R6 restore, 139 us):
// 64 edges/block, 4 waves, wave-local rows, register-prefetched gathers.
// layer 1 (MFMA, transposed): D[c][e]; layer 2 (MFMA): h2 = relu(h1@W2+b2);
// wave-local segmented reduction -> few atomics.
// ---------------------------------------------------------------------------
__global__ __launch_bounds__(256, 5) void edge_kernel(
    const unsigned short* __restrict__ Up,   // 50000 x 128 bf16
    const unsigned short* __restrict__ Vp,   // 50000 x 128 bf16
    const unsigned short* __restrict__ evs,  // E x 16 bf16, sorted
    const unsigned int* __restrict__ iuv_s,  // E packed (iu | iv<<16), sorted
    const unsigned short* __restrict__ Wef,  // layer-1 A frags (We^T, K=32 pad)
    const float* __restrict__ gb1,
    const unsigned short* __restrict__ W2f,  // layer-2 B frags
    const float* __restrict__ gb2,
    float* __restrict__ agg)
{
    __shared__ unsigned short sH1[64 * 136];  // aliased as sH2 f32 [64][68]
    __shared__ int sIu[64];

    const int tid = threadIdx.x;
    const int e0 = blockIdx.x * 64;
    const int wid = tid >> 6, lane = tid & 63;
    const int lo = lane & 15, hi = lane >> 4;
    const int g = e0 + wid * 16 + lo;         // this lane's (sorted) edge

    const unsigned iuv = iuv_s[g];
    const int iu = (int)(iuv & 0xFFFFu);
    const int iv = (int)(iuv >> 16);
    if (hi == 0) sIu[wid * 16 + lo] = iu;     // wave-local write

    // ---- register-prefetch the gathers (16 independent 8B loads) ----
    ushort4 upv[8], vpv[8];
#pragma unroll
    for (int ct = 0; ct < 8; ++ct) {
        upv[ct] = *(const ushort4*)&Up[(size_t)iu * 128 + ct * 16 + hi * 4];
        vpv[ct] = *(const ushort4*)&Vp[(size_t)iv * 128 + ct * 16 + hi * 4];
    }

    // ---- layer 1 MFMA: B-frag = evs row (coalesced); A = Wef (L1-hot) ----
    bf16x8 bfrag;
    if (hi < 2) {
        bfrag = *(const bf16x8*)&evs[(size_t)g * 16 + hi * 8];
    } else {
        bfrag = (bf16x8)(short)0;             // K-pad 16->32
    }

    f32x4 acc[8];
#pragma unroll
    for (int ct = 0; ct < 8; ++ct) {
#pragma unroll
        for (int r = 0; r < 4; ++r) acc[ct][r] = 0.f;
        bf16x8 a = *(const bf16x8*)&Wef[(size_t)((ct * 64 + lane) * 8)];
        acc[ct] = __builtin_amdgcn_mfma_f32_16x16x32_bf16(a, bfrag, acc[ct], 0, 0, 0);
    }

    // epilogue: h1 = relu(acc + b1 + Up[iu] + Vp[iv]) -> bf16 LDS (wave-local)
    const int e_loc = wid * 16 + lo;
#pragma unroll
    for (int ct = 0; ct < 8; ++ct) {
        int c0 = ct * 16 + hi * 4;
        float4 b1 = *(const float4*)&gb1[c0];
        ushort4 uv = upv[ct], vv = vpv[ct];
        ushort4 h;
        h.x = f2bf(relu(acc[ct][0] + b1.x + bf2f(uv.x) + bf2f(vv.x)));
        h.y = f2bf(relu(acc[ct][1] + b1.y + bf2f(uv.y) + bf2f(vv.y)));
        h.z = f2bf(relu(acc[ct][2] + b1.z + bf2f(uv.z) + bf2f(vv.z)));
        h.w = f2bf(relu(acc[ct][3] + b1.w + bf2f(uv.w) + bf2f(vv.w)));
        *(ushort4*)&sH1[e_loc * 136 + c0] = h;
    }
    // intra-wave ushort write->read on same array: compiler-ordered, no barrier

    // ---- layer 2 via MFMA: wave reads its OWN 16 rows of sH1 ----
    f32x4 accm[4];
#pragma unroll
    for (int nt = 0; nt < 4; ++nt)
#pragma unroll
        for (int r = 0; r < 4; ++r) accm[nt][r] = 0.f;

#pragma unroll
    for (int ks = 0; ks < 4; ++ks) {
        bf16x8 a = *(const bf16x8*)&sH1[(wid * 16 + lo) * 136 + ks * 32 + hi * 8];
#pragma unroll
        for (int nt = 0; nt < 4; ++nt) {
            bf16x8 b = *(const bf16x8*)&W2f[(size_t)(((ks * 4 + nt) * 64 + lane) * 8)];
            accm[nt] = __builtin_amdgcn_mfma_f32_16x16x32_bf16(a, b, accm[nt], 0, 0, 0);
        }
    }
    __syncthreads();   // alias (ushort->float) boundary: all sH1 reads done

    float* sH2 = (float*)sH1;   // [64][68] fp32; wave-local byte range coincides
#pragma unroll
    for (int nt = 0; nt < 4; ++nt) {
        int col = nt * 16 + lo;
        float b2v = gb2[col];
        int erow = wid * 16 + hi * 4;
#pragma unroll
        for (int r = 0; r < 4; ++r)
            sH2[(erow + r) * 68 + col] = relu(accm[nt][r] + b2v);
    }
    // reduction reads own wave's rows (float->float, intra-wave): no barrier

    // ---- segmented reduction over sorted iu: thread = (col, own wave) ----
    {
        const int c = tid & 63;       // output column
        const int eq0 = wid * 16;     // this wave's 16 edges
        int   iu_cur = sIu[eq0];
        float running = 0.f;
#pragma unroll
        for (int k = 0; k < 16; ++k) {
            int e = eq0 + k;
            int iu2 = sIu[e];
            if (iu2 != iu_cur) {
                atomicAdd(&agg[(size_t)iu_cur * 64 + c], running);
                running = 0.f;
                iu_cur = iu2;
            }
            running += sH2[e * 68 + c];
        }
        atomicAdd(&agg[(size_t)iu_cur * 64 + c], running);
    }
}

// ---------------------------------------------------------------------------
// node kernel: out = relu(relu([u, agg] @ fw1 + fb1) @ fw2 + fb2)
// ---------------------------------------------------------------------------
__global__ __launch_bounds__(256) void node_kernel(
    const float* __restrict__ u, const float* __restrict__ agg,
    const float* __restrict__ fw1, const float* __restrict__ fb1,
    const float* __restrict__ fw2, const float* __restrict__ fb2,
    float* __restrict__ out, int N)
{
    __shared__ float sX[64 * 128];  // 32 KB
    __shared__ float sY[64 * 132];  // 33 KB
    const int tid = threadIdx.x;
    const int row0 = blockIdx.x * 64;

    for (int i = tid * 4; i < 64 * 64; i += 1024) {
        int r = i >> 6, c = i & 63;
        int gr = row0 + r;
        float4 uu = (gr < N) ? *(const float4*)&u[(size_t)gr * 64 + c]
                             : make_float4(0.f, 0.f, 0.f, 0.f);
        float4 aa = (gr < N) ? *(const float4*)&agg[(size_t)gr * 64 + c]
                             : make_float4(0.f, 0.f, 0.f, 0.f);
        *(float4*)&sX[r * 128 + c] = uu;
        *(float4*)&sX[r * 128 + 64 + c] = aa;
    }
    __syncthreads();

    {
        const int cg_ = tid & 31, rg = tid >> 5;
        const int c0 = cg_ * 4, r0 = rg * 8;
        const float4 bsv = *(const float4*)&fb1[c0];
        float acc[8][4];
#pragma unroll
        for (int i = 0; i < 8; ++i) {
            acc[i][0] = bsv.x; acc[i][1] = bsv.y; acc[i][2] = bsv.z; acc[i][3] = bsv.w;
        }
#pragma unroll 4
        for (int k = 0; k < 128; ++k) {
            float4 w = *(const float4*)&fw1[k * 128 + c0];
#pragma unroll
            for (int i = 0; i < 8; ++i) {
                float x = sX[(r0 + i) * 128 + k];
                acc[i][0] += x * w.x; acc[i][1] += x * w.y;
                acc[i][2] += x * w.z; acc[i][3] += x * w.w;
            }
        }
#pragma unroll
        for (int i = 0; i < 8; ++i) {
            float4 h = make_float4(relu(acc[i][0]), relu(acc[i][1]),
                                   relu(acc[i][2]), relu(acc[i][3]));
            *(float4*)&sY[(r0 + i) * 132 + c0] = h;
        }
    }
    __syncthreads();

    {
        const int cg_ = tid & 15, rg = tid >> 4;
        const int c0 = cg_ * 4;
        const float4 bsv = *(const float4*)&fb2[c0];
        float acc[4][4];
#pragma unroll
        for (int i = 0; i < 4; ++i) {
            acc[i][0] = bsv.x; acc[i][1] = bsv.y; acc[i][2] = bsv.z; acc[i][3] = bsv.w;
        }
#pragma unroll 4
        for (int k = 0; k < 128; ++k) {
            float4 w = *(const float4*)&fw2[k * 64 + c0];
#pragma unroll
            for (int i = 0; i < 4; ++i) {
                float yv = sY[(rg * 4 + i) * 132 + k];
                acc[i][0] += yv * w.x; acc[i][1] += yv * w.y;
                acc[i][2] += yv * w.z; acc[i][3] += yv * w.w;
            }
        }
#pragma unroll
        for (int i = 0; i < 4; ++i) {
            int gr = row0 + rg * 4 + i;
            if (gr < N) {
                float4 o = make_float4(relu(acc[i][0]), relu(acc[i][1]),
                                       relu(acc[i][2]), relu(acc[i][3]));
                *(float4*)&out[(size_t)gr * 64 + c0] = o;
            }
        }
    }
}

// ---------------------------------------------------------------------------
extern "C" void kernel_launch(void* const* d_in, const int* in_sizes, int n_in,
                              void* d_out, int out_size, void* d_ws, size_t ws_size,
                              hipStream_t stream)
{
    const float* u   = (const float*)d_in[0];
    const float* v   = (const float*)d_in[1];
    const float* ev  = (const float*)d_in[2];
    const int*   eiv = (const int*)d_in[3];
    const int*   eiu = (const int*)d_in[4];
    const float* gw1 = (const float*)d_in[5];   // 144 x 128
    const float* gb1 = (const float*)d_in[6];   // 128
    const float* gw2 = (const float*)d_in[7];   // 128 x 64
    const float* gb2 = (const float*)d_in[8];   // 64
    const float* fw1 = (const float*)d_in[9];   // 128 x 128
    const float* fb1 = (const float*)d_in[10];  // 128
    const float* fw2 = (const float*)d_in[11];  // 128 x 64
    const float* fb2 = (const float*)d_in[12];  // 64
    float* out = (float*)d_out;

    // workspace layout (agg and counts adjacent -> single memset); ~67.4 MB
    unsigned short* Up     = (unsigned short*)d_ws;                 // 50000x128 bf16
    unsigned short* Vp     = Up + (size_t)U_N * 128;                // 50000x128 bf16
    unsigned short* evs    = Vp + (size_t)V_N * 128;                // E x 16 bf16
    float*          agg    = (float*)(evs + (size_t)E_N * 16);      // 50000x64 f32
    int*            counts = (int*)(agg + (size_t)U_N * 64);        // 50000 (= cursor)
    unsigned int*   iuv_s  = (unsigned int*)(counts + U_N);         // 800000
    unsigned short* W2f    = (unsigned short*)(iuv_s + E_N);        // 8192 bf16
    unsigned short* Wef    = W2f + 8192;                            // 4096 bf16

    // one memset covers agg (zero init) + counts (hist init)
    hipMemsetAsync(agg, 0, ((size_t)U_N * 64 + U_N) * sizeof(float), stream);

    dim3 blk(256);
    prep_kernel<<<dim3(2 * NB_PROJ + 1 + NB_HIST), blk, 0, stream>>>(
        eiu, counts, u, v, gw1, gw2, Up, Vp, W2f, Wef);
    scan_kernel<<<dim3(1), dim3(1024), 0, stream>>>(counts);
    permute_kernel<<<dim3(NB_HIST), blk, 0, stream>>>(
        eiu, eiv, ev, counts, iuv_s, evs);

    edge_kernel<<<dim3(E_N / 64), blk, 0, stream>>>(
        Up, Vp, evs, iuv_s, Wef, gb1, W2f, gb2, agg);
    node_kernel<<<dim3((U_N + 63) / 64), blk, 0, stream>>>(
        u, agg, fw1, fb1, fw2, fb2, out, U_N);
}

// Round 10
// 357.051 us; speedup vs baseline: 2.1399x; 1.0285x over previous
//
#include <hip/hip_runtime.h>

// Problem constants (match reference)
constexpr int U_N = 50000;
constexpr int V_N = 50000;
constexpr int E_N = 800000;   // == 128 * 6250
// dims: F=64, G=64, H=16; g: 144->128->64; f: 128->128->64

typedef float f32x4 __attribute__((ext_vector_type(4)));
typedef short bf16x8 __attribute__((ext_vector_type(8)));

__device__ __forceinline__ float relu(float x) { return fmaxf(x, 0.f); }

// round-to-nearest-even fp32 -> bf16 bits
__device__ __forceinline__ unsigned short f2bf(float f) {
    unsigned u = __float_as_uint(f);
    unsigned rounding = 0x7FFFu + ((u >> 16) & 1u);
    return (unsigned short)((u + rounding) >> 16);
}
__device__ __forceinline__ float bf2f(unsigned short b) {
    return __uint_as_float(((unsigned)b) << 16);
}

constexpr int NB_HIST = (E_N + 255) / 256;   // 3125
constexpr int NB_PROJ = (U_N + 63) / 64;     // 782

// ---------------------------------------------------------------------------
// proj via MFMA: P[row0..row0+64][128] = bf16(X[.][64]) @ bf16(W[64][128])
// (unchanged from R9 — verified)
// ---------------------------------------------------------------------------
__device__ __forceinline__ void proj_mfma(const float* __restrict__ X,
                                          const float* __restrict__ W,  // 64x128
                                          unsigned short* __restrict__ P,
                                          int N, int row0,
                                          unsigned short* sWf)
{
    const int tid = threadIdx.x;

    for (int idx = tid; idx < 64 * 128 / 4; idx += 256) {
        int k  = (idx * 4) >> 7;
        int n0 = (idx * 4) & 127;
        float4 w = *(const float4*)&W[k * 128 + n0];
        int ks = k >> 5, hi = (k & 31) >> 3, j = k & 7;
        float wv[4] = {w.x, w.y, w.z, w.w};
#pragma unroll
        for (int q = 0; q < 4; ++q) {
            int n = n0 + q, nt = n >> 4, lo = n & 15;
            sWf[((ks * 8 + nt) * 64 + hi * 16 + lo) * 8 + j] = f2bf(wv[q]);
        }
    }
    __syncthreads();

    const int wid = tid >> 6, lane = tid & 63;
    const int lo = lane & 15, hi = lane >> 4;
    const int row = row0 + wid * 16 + lo;
    const int rl = (row < N) ? row : (N - 1);

    bf16x8 a0, a1;
    {
        union { bf16x8 v; unsigned short s[8]; } ra, rb;
        float4 x0 = *(const float4*)&X[(size_t)rl * 64 + hi * 8];
        float4 x1 = *(const float4*)&X[(size_t)rl * 64 + hi * 8 + 4];
        ra.s[0] = f2bf(x0.x); ra.s[1] = f2bf(x0.y); ra.s[2] = f2bf(x0.z); ra.s[3] = f2bf(x0.w);
        ra.s[4] = f2bf(x1.x); ra.s[5] = f2bf(x1.y); ra.s[6] = f2bf(x1.z); ra.s[7] = f2bf(x1.w);
        float4 y0 = *(const float4*)&X[(size_t)rl * 64 + 32 + hi * 8];
        float4 y1 = *(const float4*)&X[(size_t)rl * 64 + 32 + hi * 8 + 4];
        rb.s[0] = f2bf(y0.x); rb.s[1] = f2bf(y0.y); rb.s[2] = f2bf(y0.z); rb.s[3] = f2bf(y0.w);
        rb.s[4] = f2bf(y1.x); rb.s[5] = f2bf(y1.y); rb.s[6] = f2bf(y1.z); rb.s[7] = f2bf(y1.w);
        a0 = ra.v; a1 = rb.v;
    }

    const int rbase = row0 + wid * 16 + hi * 4;
#pragma unroll
    for (int nt = 0; nt < 8; ++nt) {
        f32x4 acc;
#pragma unroll
        for (int r = 0; r < 4; ++r) acc[r] = 0.f;
        bf16x8 b0 = *(const bf16x8*)&sWf[((0 * 8 + nt) * 64 + lane) * 8];
        bf16x8 b1 = *(const bf16x8*)&sWf[((1 * 8 + nt) * 64 + lane) * 8];
        acc = __builtin_amdgcn_mfma_f32_16x16x32_bf16(a0, b0, acc, 0, 0, 0);
        acc = __builtin_amdgcn_mfma_f32_16x16x32_bf16(a1, b1, acc, 0, 0, 0);
#pragma unroll
        for (int r = 0; r < 4; ++r) {
            int gr = rbase + r;
            if (gr < N) P[(size_t)gr * 128 + nt * 16 + lo] = f2bf(acc[r]);
        }
    }
}

// ---------------------------------------------------------------------------
// prep kernel: projU (MFMA), projV (MFMA), weight-pack, histogram.
// Weight-pack now also emits F1f/F2f (node-MLP fragment-major bf16).
// ---------------------------------------------------------------------------
__global__ __launch_bounds__(256) void prep_kernel(
    const int* __restrict__ idx_u, int* __restrict__ counts,
    const float* __restrict__ u, const float* __restrict__ v,
    const float* __restrict__ gw1, const float* __restrict__ gw2,
    const float* __restrict__ fw1, const float* __restrict__ fw2,
    unsigned short* __restrict__ Up, unsigned short* __restrict__ Vp,
    unsigned short* __restrict__ W2f, unsigned short* __restrict__ Wef,
    unsigned short* __restrict__ F1f, unsigned short* __restrict__ F2f)
{
    __shared__ unsigned short sWf[8192];   // proj branches only
    int b = blockIdx.x;

    if (b < NB_PROJ) {
        proj_mfma(u, gw1, Up, U_N, b * 64, sWf);
        return;
    }
    b -= NB_PROJ;
    if (b < NB_PROJ) {
        proj_mfma(v, gw1 + 64 * 128, Vp, V_N, b * 64, sWf);
        return;
    }
    b -= NB_PROJ;
    if (b == 0) {
        const int tid = threadIdx.x;
        // W2f (edge L2, gw2 128x64) and F2f (node L2, fw2 128x64): same layout
        for (int t = tid; t < 4 * 4 * 64 * 8; t += 256) {
            int j    = t & 7;
            int lane = (t >> 3) & 63;
            int nt   = (t >> 9) & 3;
            int ks   = t >> 11;
            int n = nt * 16 + (lane & 15);
            int k = ks * 32 + (lane >> 4) * 8 + j;
            W2f[t] = f2bf(gw2[k * 64 + n]);
            F2f[t] = f2bf(fw2[k * 64 + n]);
        }
        // Wef (edge L1 A-frags, We^T, K padded to 32)
        const float* gw1e = gw1 + 128 * 128;   // 16 x 128
        for (int t = tid; t < 8 * 64 * 8; t += 256) {
            int j    = t & 7;
            int lane = (t >> 3) & 63;
            int ct   = t >> 9;
            int c = ct * 16 + (lane & 15);
            int k = (lane >> 4) * 8 + j;
            Wef[t] = (k < 16) ? f2bf(gw1e[k * 128 + c]) : (unsigned short)0;
        }
        // F1f (node L1, fw1 128x128): ks 0..3, nt 0..7
        for (int t = tid; t < 4 * 8 * 64 * 8; t += 256) {
            int j    = t & 7;
            int lane = (t >> 3) & 63;
            int nt   = (t >> 9) & 7;
            int ks   = t >> 12;
            int n = nt * 16 + (lane & 15);
            int k = ks * 32 + (lane >> 4) * 8 + j;
            F1f[t] = f2bf(fw1[k * 128 + n]);
        }
        return;
    }
    b -= 1;
    // ---- histogram ----
    int e = b * 256 + threadIdx.x;
    if (e < E_N) atomicAdd(&counts[idx_u[e]], 1);
}

// ---------------------------------------------------------------------------
// single block, 1024 threads: in-place exclusive scan of counts[0..U_N)
// ---------------------------------------------------------------------------
__global__ __launch_bounds__(1024) void scan_kernel(int* __restrict__ counts)
{
    __shared__ int sPart[1024];
    const int tid = threadIdx.x;
    constexpr int CH = 49;          // 1024*49 = 50176 >= 50000
    const int base = tid * CH;

    int sum = 0;
#pragma unroll
    for (int k = 0; k < CH; ++k) {
        int i = base + k;
        if (i < U_N) sum += counts[i];
    }
    sPart[tid] = sum;
    __syncthreads();
    for (int off = 1; off < 1024; off <<= 1) {
        int val = (tid >= off) ? sPart[tid - off] : 0;
        __syncthreads();
        sPart[tid] += val;
        __syncthreads();
    }
    int run = sPart[tid] - sum;     // exclusive prefix for this chunk
    for (int k = 0; k < CH; ++k) {
        int i = base + k;
        if (i < U_N) { int c = counts[i]; counts[i] = run; run += c; }
    }
}

// ---------------------------------------------------------------------------
// permute+gather: scatter edges into sorted order, pre-gathering everything
// the edge kernel needs: iuv packed indices + ev row as bf16.
// ---------------------------------------------------------------------------
__global__ __launch_bounds__(256) void permute_kernel(
    const int* __restrict__ idx_u, const int* __restrict__ idx_v,
    const float* __restrict__ ev, int* __restrict__ cursor,
    unsigned int* __restrict__ iuv_s, unsigned short* __restrict__ evs)
{
    int e = blockIdx.x * 256 + threadIdx.x;
    if (e >= E_N) return;
    int iu = idx_u[e];
    int iv = idx_v[e];
    int pos = atomicAdd(&cursor[iu], 1);
    iuv_s[pos] = (unsigned)iu | ((unsigned)iv << 16);

    const float* src = &ev[(size_t)e * 16];
    unsigned short* dst = &evs[(size_t)pos * 16];
#pragma unroll
    for (int q = 0; q < 4; ++q) {
        float4 a = *(const float4*)&src[q * 4];
        ushort4 o;
        o.x = f2bf(a.x); o.y = f2bf(a.y); o.z = f2bf(a.z); o.w = f2bf(a.w);
        *(ushort4*)&dst[q * 4] = o;
    }
}

// ---------------------------------------------------------------------------
// edge kernel: 128 sorted edges/block, 4 waves, TWO edges per lane (A and B).
// Both edges' Vp gathers issued up front -> 2x memory-level parallelism of R6.
// Flat named registers (no runtime-indexed buffers, rule #20); zero barriers
// (all LDS wave-local; DS ops in-order within a wave).
// ---------------------------------------------------------------------------
__global__ __launch_bounds__(256, 4) void edge_kernel(
    const unsigned short* __restrict__ Up,   // 50000 x 128 bf16
    const unsigned short* __restrict__ Vp,   // 50000 x 128 bf16
    const unsigned short* __restrict__ evs,  // E x 16 bf16, sorted
    const unsigned int* __restrict__ iuv_s,  // E packed (iu | iv<<16), sorted
    const unsigned short* __restrict__ Wef,  // layer-1 A frags (We^T, K=32 pad)
    const float* __restrict__ gb1,
    const unsigned short* __restrict__ W2f,  // layer-2 B frags
    const float* __restrict__ gb2,
    float* __restrict__ agg)
{
    __shared__ unsigned short sH1[128 * 136];  // aliased as sH2 f32 [128][68]
    __shared__ int sIu[128];

    const int tid = threadIdx.x;
    const int e0 = blockIdx.x * 128;
    const int wid = tid >> 6, lane = tid & 63;
    const int lo = lane & 15, hi = lane >> 4;
    const int gA = e0 + wid * 32 + lo;        // lane's edge A
    const int gB = gA + 16;                   // lane's edge B

    const unsigned iuvA = iuv_s[gA];
    const unsigned iuvB = iuv_s[gB];
    const int iuA = (int)(iuvA & 0xFFFFu), ivA = (int)(iuvA >> 16);
    const int iuB = (int)(iuvB & 0xFFFFu), ivB = (int)(iuvB >> 16);
    if (hi == 0) {
        sIu[wid * 32 + lo] = iuA;             // wave-local writes
        sIu[wid * 32 + 16 + lo] = iuB;
    }

    // ---- prefetch BOTH edges' Vp rows (32 independent 8B loads) ----
    ushort4 vpA[8], vpB[8];
#pragma unroll
    for (int ct = 0; ct < 8; ++ct) {
        vpA[ct] = *(const ushort4*)&Vp[(size_t)ivA * 128 + ct * 16 + hi * 4];
        vpB[ct] = *(const ushort4*)&Vp[(size_t)ivB * 128 + ct * 16 + hi * 4];
    }
    bf16x8 bfA = (hi < 2) ? *(const bf16x8*)&evs[(size_t)gA * 16 + hi * 8]
                          : (bf16x8)(short)0;
    bf16x8 bfB = (hi < 2) ? *(const bf16x8*)&evs[(size_t)gB * 16 + hi * 8]
                          : (bf16x8)(short)0;

    const int eA = wid * 32 + lo;             // LDS row for edge A
    const int eB = eA + 16;                   // LDS row for edge B

    // ======== edge A: layer 1 MFMA + epilogue ========
    {
        f32x4 acc[8];
#pragma unroll
        for (int ct = 0; ct < 8; ++ct) {
#pragma unroll
            for (int r = 0; r < 4; ++r) acc[ct][r] = 0.f;
            bf16x8 a = *(const bf16x8*)&Wef[(size_t)((ct * 64 + lane) * 8)];
            acc[ct] = __builtin_amdgcn_mfma_f32_16x16x32_bf16(a, bfA, acc[ct], 0, 0, 0);
        }
#pragma unroll
        for (int ct = 0; ct < 8; ++ct) {
            int c0 = ct * 16 + hi * 4;
            ushort4 uv = *(const ushort4*)&Up[(size_t)iuA * 128 + c0];  // cache-hot
            float4 b1 = *(const float4*)&gb1[c0];
            ushort4 vv = vpA[ct];
            ushort4 h;
            h.x = f2bf(relu(acc[ct][0] + b1.x + bf2f(uv.x) + bf2f(vv.x)));
            h.y = f2bf(relu(acc[ct][1] + b1.y + bf2f(uv.y) + bf2f(vv.y)));
            h.z = f2bf(relu(acc[ct][2] + b1.z + bf2f(uv.z) + bf2f(vv.z)));
            h.w = f2bf(relu(acc[ct][3] + b1.w + bf2f(uv.w) + bf2f(vv.w)));
            *(ushort4*)&sH1[eA * 136 + c0] = h;
        }
    }

    // ======== edge B: layer 1 MFMA + epilogue ========
    {
        f32x4 acc[8];
#pragma unroll
        for (int ct = 0; ct < 8; ++ct) {
#pragma unroll
            for (int r = 0; r < 4; ++r) acc[ct][r] = 0.f;
            bf16x8 a = *(const bf16x8*)&Wef[(size_t)((ct * 64 + lane) * 8)];
            acc[ct] = __builtin_amdgcn_mfma_f32_16x16x32_bf16(a, bfB, acc[ct], 0, 0, 0);
        }
#pragma unroll
        for (int ct = 0; ct < 8; ++ct) {
            int c0 = ct * 16 + hi * 4;
            ushort4 uv = *(const ushort4*)&Up[(size_t)iuB * 128 + c0];
            float4 b1 = *(const float4*)&gb1[c0];
            ushort4 vv = vpB[ct];
            ushort4 h;
            h.x = f2bf(relu(acc[ct][0] + b1.x + bf2f(uv.x) + bf2f(vv.x)));
            h.y = f2bf(relu(acc[ct][1] + b1.y + bf2f(uv.y) + bf2f(vv.y)));
            h.z = f2bf(relu(acc[ct][2] + b1.z + bf2f(uv.z) + bf2f(vv.z)));
            h.w = f2bf(relu(acc[ct][3] + b1.w + bf2f(uv.w) + bf2f(vv.w)));
            *(ushort4*)&sH1[eB * 136 + c0] = h;
        }
    }

    float* const sH2 = (float*)sH1;   // [128][68] f32; wave-local byte ranges

    // ======== layer 2, group A (rows wid*32 .. +15) ========
    {
        f32x4 accm[4];
#pragma unroll
        for (int nt = 0; nt < 4; ++nt)
#pragma unroll
            for (int r = 0; r < 4; ++r) accm[nt][r] = 0.f;
#pragma unroll
        for (int ks = 0; ks < 4; ++ks) {
            bf16x8 a = *(const bf16x8*)&sH1[eA * 136 + ks * 32 + hi * 8];
#pragma unroll
            for (int nt = 0; nt < 4; ++nt) {
                bf16x8 b = *(const bf16x8*)&W2f[(size_t)(((ks * 4 + nt) * 64 + lane) * 8)];
                accm[nt] = __builtin_amdgcn_mfma_f32_16x16x32_bf16(a, b, accm[nt], 0, 0, 0);
            }
        }
        // overwrite group-A bytes only (reads of them are done via reg deps)
#pragma unroll
        for (int nt = 0; nt < 4; ++nt) {
            int col = nt * 16 + lo;
            float b2v = gb2[col];
            int erow = wid * 32 + hi * 4;
#pragma unroll
            for (int r = 0; r < 4; ++r)
                sH2[(erow + r) * 68 + col] = relu(accm[nt][r] + b2v);
        }
    }

    // ======== layer 2, group B (rows wid*32+16 .. +31) ========
    {
        f32x4 accm[4];
#pragma unroll
        for (int nt = 0; nt < 4; ++nt)
#pragma unroll
            for (int r = 0; r < 4; ++r) accm[nt][r] = 0.f;
#pragma unroll
        for (int ks = 0; ks < 4; ++ks) {
            bf16x8 a = *(const bf16x8*)&sH1[eB * 136 + ks * 32 + hi * 8];
#pragma unroll
            for (int nt = 0; nt < 4; ++nt) {
                bf16x8 b = *(const bf16x8*)&W2f[(size_t)(((ks * 4 + nt) * 64 + lane) * 8)];
                accm[nt] = __builtin_amdgcn_mfma_f32_16x16x32_bf16(a, b, accm[nt], 0, 0, 0);
            }
        }
#pragma unroll
        for (int nt = 0; nt < 4; ++nt) {
            int col = nt * 16 + lo;
            float b2v = gb2[col];
            int erow = wid * 32 + 16 + hi * 4;
#pragma unroll
            for (int r = 0; r < 4; ++r)
                sH2[(erow + r) * 68 + col] = relu(accm[nt][r] + b2v);
        }
    }

    // ---- segmented reduction over this wave's 32 sorted edges ----
    {
        const int c = lane;           // output column
        const int eq0 = wid * 32;
        int   iu_cur = sIu[eq0];
        float running = 0.f;
#pragma unroll
        for (int k = 0; k < 32; ++k) {
            int iu2 = sIu[eq0 + k];
            if (iu2 != iu_cur) {
                atomicAdd(&agg[(size_t)iu_cur * 64 + c], running);
                running = 0.f;
                iu_cur = iu2;
            }
            running += sH2[(eq0 + k) * 68 + c];
        }
        atomicAdd(&agg[(size_t)iu_cur * 64 + c], running);
    }
}

// ---------------------------------------------------------------------------
// node kernel via MFMA: out = relu(relu([u,agg] @ fw1 + fb1) @ fw2 + fb2)
// Same fragment scheme as edge layer-2. y staged bf16 wave-local; no barriers.
// ---------------------------------------------------------------------------
__global__ __launch_bounds__(256) void node_kernel(
    const float* __restrict__ u, const float* __restrict__ agg,
    const unsigned short* __restrict__ F1f, const float* __restrict__ fb1,
    const unsigned short* __restrict__ F2f, const float* __restrict__ fb2,
    float* __restrict__ out, int N)
{
    __shared__ unsigned short sY[64 * 136];   // y bf16, wave-local rows
    const int tid = threadIdx.x;
    const int wid = tid >> 6, lane = tid & 63;
    const int lo = lane & 15, hi = lane >> 4;
    const int row0 = blockIdx.x * 64;
    const int row = row0 + wid * 16 + lo;
    const int rl = (row < N) ? row : (N - 1);

    // A-frags: ks0,1 from u (cols 0..63), ks2,3 from agg (cols 0..63)
    bf16x8 a0, a1, a2, a3;
    {
        union { bf16x8 v; unsigned short s[8]; } r0_, r1_, r2_, r3_;
        float4 x0 = *(const float4*)&u[(size_t)rl * 64 + hi * 8];
        float4 x1 = *(const float4*)&u[(size_t)rl * 64 + hi * 8 + 4];
        float4 x2 = *(const float4*)&u[(size_t)rl * 64 + 32 + hi * 8];
        float4 x3 = *(const float4*)&u[(size_t)rl * 64 + 32 + hi * 8 + 4];
        float4 g0 = *(const float4*)&agg[(size_t)rl * 64 + hi * 8];
        float4 g1 = *(const float4*)&agg[(size_t)rl * 64 + hi * 8 + 4];
        float4 g2 = *(const float4*)&agg[(size_t)rl * 64 + 32 + hi * 8];
        float4 g3 = *(const float4*)&agg[(size_t)rl * 64 + 32 + hi * 8 + 4];
        r0_.s[0] = f2bf(x0.x); r0_.s[1] = f2bf(x0.y); r0_.s[2] = f2bf(x0.z); r0_.s[3] = f2bf(x0.w);
        r0_.s[4] = f2bf(x1.x); r0_.s[5] = f2bf(x1.y); r0_.s[6] = f2bf(x1.z); r0_.s[7] = f2bf(x1.w);
        r1_.s[0] = f2bf(x2.x); r1_.s[1] = f2bf(x2.y); r1_.s[2] = f2bf(x2.z); r1_.s[3] = f2bf(x2.w);
        r1_.s[4] = f2bf(x3.x); r1_.s[5] = f2bf(x3.y); r1_.s[6] = f2bf(x3.z); r1_.s[7] = f2bf(x3.w);
        r2_.s[0] = f2bf(g0.x); r2_.s[1] = f2bf(g0.y); r2_.s[2] = f2bf(g0.z); r2_.s[3] = f2bf(g0.w);
        r2_.s[4] = f2bf(g1.x); r2_.s[5] = f2bf(g1.y); r2_.s[6] = f2bf(g1.z); r2_.s[7] = f2bf(g1.w);
        r3_.s[0] = f2bf(g2.x); r3_.s[1] = f2bf(g2.y); r3_.s[2] = f2bf(g2.z); r3_.s[3] = f2bf(g2.w);
        r3_.s[4] = f2bf(g3.x); r3_.s[5] = f2bf(g3.y); r3_.s[6] = f2bf(g3.z); r3_.s[7] = f2bf(g3.w);
        a0 = r0_.v; a1 = r1_.v; a2 = r2_.v; a3 = r3_.v;
    }

    // ---- layer 1: y = relu(x @ fw1 + fb1), 32 MFMAs/wave ----
#pragma unroll
    for (int nt = 0; nt < 8; ++nt) {
        f32x4 acc;
#pragma unroll
        for (int r = 0; r < 4; ++r) acc[r] = 0.f;
        bf16x8 b0 = *(const bf16x8*)&F1f[(size_t)(((0 * 8 + nt) * 64 + lane) * 8)];
        bf16x8 b1 = *(const bf16x8*)&F1f[(size_t)(((1 * 8 + nt) * 64 + lane) * 8)];
        bf16x8 b2 = *(const bf16x8*)&F1f[(size_t)(((2 * 8 + nt) * 64 + lane) * 8)];
        bf16x8 b3 = *(const bf16x8*)&F1f[(size_t)(((3 * 8 + nt) * 64 + lane) * 8)];
        acc = __builtin_amdgcn_mfma_f32_16x16x32_bf16(a0, b0, acc, 0, 0, 0);
        acc = __builtin_amdgcn_mfma_f32_16x16x32_bf16(a1, b1, acc, 0, 0, 0);
        acc = __builtin_amdgcn_mfma_f32_16x16x32_bf16(a2, b2, acc, 0, 0, 0);
        acc = __builtin_amdgcn_mfma_f32_16x16x32_bf16(a3, b3, acc, 0, 0, 0);
        int col = nt * 16 + lo;
        float b1v = fb1[col];
        int rbase = wid * 16 + hi * 4;
#pragma unroll
        for (int r = 0; r < 4; ++r)
            sY[(rbase + r) * 136 + col] = f2bf(relu(acc[r] + b1v));
    }

    // ---- layer 2: out = relu(y @ fw2 + fb2), 16 MFMAs/wave ----
    bf16x8 ya0 = *(const bf16x8*)&sY[(wid * 16 + lo) * 136 + 0 * 32 + hi * 8];
    bf16x8 ya1 = *(const bf16x8*)&sY[(wid * 16 + lo) * 136 + 1 * 32 + hi * 8];
    bf16x8 ya2 = *(const bf16x8*)&sY[(wid * 16 + lo) * 136 + 2 * 32 + hi * 8];
    bf16x8 ya3 = *(const bf16x8*)&sY[(wid * 16 + lo) * 136 + 3 * 32 + hi * 8];
#pragma unroll
    for (int nt = 0; nt < 4; ++nt) {
        f32x4 acc;
#pragma unroll
        for (int r = 0; r < 4; ++r) acc[r] = 0.f;
        bf16x8 b0 = *(const bf16x8*)&F2f[(size_t)(((0 * 4 + nt) * 64 + lane) * 8)];
        bf16x8 b1 = *(const bf16x8*)&F2f[(size_t)(((1 * 4 + nt) * 64 + lane) * 8)];
        bf16x8 b2 = *(const bf16x8*)&F2f[(size_t)(((2 * 4 + nt) * 64 + lane) * 8)];
        bf16x8 b3 = *(const bf16x8*)&F2f[(size_t)(((3 * 4 + nt) * 64 + lane) * 8)];
        acc = __builtin_amdgcn_mfma_f32_16x16x32_bf16(ya0, b0, acc, 0, 0, 0);
        acc = __builtin_amdgcn_mfma_f32_16x16x32_bf16(ya1, b1, acc, 0, 0, 0);
        acc = __builtin_amdgcn_mfma_f32_16x16x32_bf16(ya2, b2, acc, 0, 0, 0);
        acc = __builtin_amdgcn_mfma_f32_16x16x32_bf16(ya3, b3, acc, 0, 0, 0);
        int col = nt * 16 + lo;
        float b2v = fb2[col];
#pragma unroll
        for (int r = 0; r < 4; ++r) {
            int gr = row0 + wid * 16 + hi * 4 + r;
            if (gr < N) out[(size_t)gr * 64 + col] = relu(acc[r] + b2v);
        }
    }
}

// ---------------------------------------------------------------------------
extern "C" void kernel_launch(void* const* d_in, const int* in_sizes, int n_in,
                              void* d_out, int out_size, void* d_ws, size_t ws_size,
                              hipStream_t stream)
{
    const float* u   = (const float*)d_in[0];
    const float* v   = (const float*)d_in[1];
    const float* ev  = (const float*)d_in[2];
    const int*   eiv = (const int*)d_in[3];
    const int*   eiu = (const int*)d_in[4];
    const float* gw1 = (const float*)d_in[5];   // 144 x 128
    const float* gb1 = (const float*)d_in[6];   // 128
    const float* gw2 = (const float*)d_in[7];   // 128 x 64
    const float* gb2 = (const float*)d_in[8];   // 64
    const float* fw1 = (const float*)d_in[9];   // 128 x 128
    const float* fb1 = (const float*)d_in[10];  // 128
    const float* fw2 = (const float*)d_in[11];  // 128 x 64
    const float* fb2 = (const float*)d_in[12];  // 64
    float* out = (float*)d_out;

    // workspace layout (agg and counts adjacent -> single memset); ~67.5 MB
    unsigned short* Up     = (unsigned short*)d_ws;                 // 50000x128 bf16
    unsigned short* Vp     = Up + (size_t)U_N * 128;                // 50000x128 bf16
    unsigned short* evs    = Vp + (size_t)V_N * 128;                // E x 16 bf16
    float*          agg    = (float*)(evs + (size_t)E_N * 16);      // 50000x64 f32
    int*            counts = (int*)(agg + (size_t)U_N * 64);        // 50000 (= cursor)
    unsigned int*   iuv_s  = (unsigned int*)(counts + U_N);         // 800000
    unsigned short* W2f    = (unsigned short*)(iuv_s + E_N);        // 8192 bf16
    unsigned short* Wef    = W2f + 8192;                            // 4096 bf16
    unsigned short* F1f    = Wef + 4096;                            // 16384 bf16
    unsigned short* F2f    = F1f + 16384;                           // 8192 bf16

    // one memset covers agg (zero init) + counts (hist init)
    hipMemsetAsync(agg, 0, ((size_t)U_N * 64 + U_N) * sizeof(float), stream);

    dim3 blk(256);
    prep_kernel<<<dim3(2 * NB_PROJ + 1 + NB_HIST), blk, 0, stream>>>(
        eiu, counts, u, v, gw1, gw2, fw1, fw2, Up, Vp, W2f, Wef, F1f, F2f);
    scan_kernel<<<dim3(1), dim3(1024), 0, stream>>>(counts);
    permute_kernel<<<dim3(NB_HIST), blk, 0, stream>>>(
        eiu, eiv, ev, counts, iuv_s, evs);

    edge_kernel<<<dim3(E_N / 128), blk, 0, stream>>>(
        Up, Vp, evs, iuv_s, Wef, gb1, W2f, gb2, agg);
    node_kernel<<<dim3((U_N + 63) / 64), blk, 0, stream>>>(
        u, agg, F1f, fb1, F2f, fb2, out, U_N);
}

// Round 11
// 277.110 us; speedup vs baseline: 2.7572x; 1.2885x over previous
//
#include <hip/hip_runtime.h>

// Problem constants (match reference)
constexpr int U_N = 50000;
constexpr int V_N = 50000;
constexpr int E_N = 800000;   // == 64 * 12500
// dims: F=64, G=64, H=16; g: 144->128->64; f: 128->128->64

typedef float f32x4 __attribute__((ext_vector_type(4)));
typedef short bf16x8 __attribute__((ext_vector_type(8)));

__device__ __forceinline__ float relu(float x) { return fmaxf(x, 0.f); }

// round-to-nearest-even fp32 -> bf16 bits
__device__ __forceinline__ unsigned short f2bf(float f) {
    unsigned u = __float_as_uint(f);
    unsigned rounding = 0x7FFFu + ((u >> 16) & 1u);
    return (unsigned short)((u + rounding) >> 16);
}
__device__ __forceinline__ float bf2f(unsigned short b) {
    return __uint_as_float(((unsigned)b) << 16);
}

constexpr int NB_HIST = (E_N + 255) / 256;   // 3125
constexpr int NB_PROJ = (U_N + 63) / 64;     // 782

// Bucketed sort: key = (iv>>13)*U_N + iu. 7 buckets -> Vp slice 2.1 MB (L2-fit).
constexpr int VSHIFT  = 13;
constexpr int NBUCKET = ((V_N - 1) >> VSHIFT) + 1;     // 7
constexpr int NBINS   = NBUCKET * U_N;                 // 350000
constexpr int NSCAN   = (NBINS + 1023) / 1024;         // 342 (fits 512-thread scan)

// ---------------------------------------------------------------------------
// proj via MFMA: P[row0..row0+64][128] = bf16(X[.][64]) @ bf16(W[64][128])
// ---------------------------------------------------------------------------
__device__ __forceinline__ void proj_mfma(const float* __restrict__ X,
                                          const float* __restrict__ W,  // 64x128
                                          unsigned short* __restrict__ P,
                                          int N, int row0,
                                          unsigned short* sWf)
{
    const int tid = threadIdx.x;

    for (int idx = tid; idx < 64 * 128 / 4; idx += 256) {
        int k  = (idx * 4) >> 7;
        int n0 = (idx * 4) & 127;
        float4 w = *(const float4*)&W[k * 128 + n0];
        int ks = k >> 5, hi = (k & 31) >> 3, j = k & 7;
        float wv[4] = {w.x, w.y, w.z, w.w};
#pragma unroll
        for (int q = 0; q < 4; ++q) {
            int n = n0 + q, nt = n >> 4, lo = n & 15;
            sWf[((ks * 8 + nt) * 64 + hi * 16 + lo) * 8 + j] = f2bf(wv[q]);
        }
    }
    __syncthreads();

    const int wid = tid >> 6, lane = tid & 63;
    const int lo = lane & 15, hi = lane >> 4;
    const int row = row0 + wid * 16 + lo;
    const int rl = (row < N) ? row : (N - 1);

    bf16x8 a0, a1;
    {
        union { bf16x8 v; unsigned short s[8]; } ra, rb;
        float4 x0 = *(const float4*)&X[(size_t)rl * 64 + hi * 8];
        float4 x1 = *(const float4*)&X[(size_t)rl * 64 + hi * 8 + 4];
        ra.s[0] = f2bf(x0.x); ra.s[1] = f2bf(x0.y); ra.s[2] = f2bf(x0.z); ra.s[3] = f2bf(x0.w);
        ra.s[4] = f2bf(x1.x); ra.s[5] = f2bf(x1.y); ra.s[6] = f2bf(x1.z); ra.s[7] = f2bf(x1.w);
        float4 y0 = *(const float4*)&X[(size_t)rl * 64 + 32 + hi * 8];
        float4 y1 = *(const float4*)&X[(size_t)rl * 64 + 32 + hi * 8 + 4];
        rb.s[0] = f2bf(y0.x); rb.s[1] = f2bf(y0.y); rb.s[2] = f2bf(y0.z); rb.s[3] = f2bf(y0.w);
        rb.s[4] = f2bf(y1.x); rb.s[5] = f2bf(y1.y); rb.s[6] = f2bf(y1.z); rb.s[7] = f2bf(y1.w);
        a0 = ra.v; a1 = rb.v;
    }

    const int rbase = row0 + wid * 16 + hi * 4;
#pragma unroll
    for (int nt = 0; nt < 8; ++nt) {
        f32x4 acc;
#pragma unroll
        for (int r = 0; r < 4; ++r) acc[r] = 0.f;
        bf16x8 b0 = *(const bf16x8*)&sWf[((0 * 8 + nt) * 64 + lane) * 8];
        bf16x8 b1 = *(const bf16x8*)&sWf[((1 * 8 + nt) * 64 + lane) * 8];
        acc = __builtin_amdgcn_mfma_f32_16x16x32_bf16(a0, b0, acc, 0, 0, 0);
        acc = __builtin_amdgcn_mfma_f32_16x16x32_bf16(a1, b1, acc, 0, 0, 0);
#pragma unroll
        for (int r = 0; r < 4; ++r) {
            int gr = rbase + r;
            if (gr < N) P[(size_t)gr * 128 + nt * 16 + lo] = f2bf(acc[r]);
        }
    }
}

// ---------------------------------------------------------------------------
// prep kernel: projU (MFMA), projV (MFMA), weight-pack, bucketed histogram.
// ---------------------------------------------------------------------------
__global__ __launch_bounds__(256) void prep_kernel(
    const int* __restrict__ idx_u, const int* __restrict__ idx_v,
    int* __restrict__ counts,
    const float* __restrict__ u, const float* __restrict__ v,
    const float* __restrict__ gw1, const float* __restrict__ gw2,
    const float* __restrict__ fw1, const float* __restrict__ fw2,
    unsigned short* __restrict__ Up, unsigned short* __restrict__ Vp,
    unsigned short* __restrict__ W2f, unsigned short* __restrict__ Wef,
    unsigned short* __restrict__ F1f, unsigned short* __restrict__ F2f)
{
    __shared__ unsigned short sWf[8192];   // proj branches only
    int b = blockIdx.x;

    if (b < NB_PROJ) {
        proj_mfma(u, gw1, Up, U_N, b * 64, sWf);
        return;
    }
    b -= NB_PROJ;
    if (b < NB_PROJ) {
        proj_mfma(v, gw1 + 64 * 128, Vp, V_N, b * 64, sWf);
        return;
    }
    b -= NB_PROJ;
    if (b == 0) {
        const int tid = threadIdx.x;
        // W2f (edge L2, gw2 128x64) and F2f (node L2, fw2 128x64): same layout
        for (int t = tid; t < 4 * 4 * 64 * 8; t += 256) {
            int j    = t & 7;
            int lane = (t >> 3) & 63;
            int nt   = (t >> 9) & 3;
            int ks   = t >> 11;
            int n = nt * 16 + (lane & 15);
            int k = ks * 32 + (lane >> 4) * 8 + j;
            W2f[t] = f2bf(gw2[k * 64 + n]);
            F2f[t] = f2bf(fw2[k * 64 + n]);
        }
        // Wef (edge L1 A-frags, We^T, K padded to 32)
        const float* gw1e = gw1 + 128 * 128;   // 16 x 128
        for (int t = tid; t < 8 * 64 * 8; t += 256) {
            int j    = t & 7;
            int lane = (t >> 3) & 63;
            int ct   = t >> 9;
            int c = ct * 16 + (lane & 15);
            int k = (lane >> 4) * 8 + j;
            Wef[t] = (k < 16) ? f2bf(gw1e[k * 128 + c]) : (unsigned short)0;
        }
        // F1f (node L1, fw1 128x128): ks 0..3, nt 0..7
        for (int t = tid; t < 4 * 8 * 64 * 8; t += 256) {
            int j    = t & 7;
            int lane = (t >> 3) & 63;
            int nt   = (t >> 9) & 7;
            int ks   = t >> 12;
            int n = nt * 16 + (lane & 15);
            int k = ks * 32 + (lane >> 4) * 8 + j;
            F1f[t] = f2bf(fw1[k * 128 + n]);
        }
        return;
    }
    b -= 1;
    // ---- bucketed histogram ----
    int e = b * 256 + threadIdx.x;
    if (e < E_N) {
        int key = (idx_v[e] >> VSHIFT) * U_N + idx_u[e];
        atomicAdd(&counts[key], 1);
    }
}

// ---------------------------------------------------------------------------
// multi-block exclusive scan of counts[0..NBINS): sums -> scan sums -> apply
// ---------------------------------------------------------------------------
__global__ __launch_bounds__(256) void scan_sums(const int* __restrict__ counts,
                                                 int* __restrict__ bsum)
{
    __shared__ int sred[256];
    const int tid = threadIdx.x;
    int base = blockIdx.x * 1024 + tid * 4;
    int s = 0;
    if (base + 3 < NBINS) {
        int4 c = *(const int4*)&counts[base];
        s = c.x + c.y + c.z + c.w;
    } else {
#pragma unroll
        for (int k = 0; k < 4; ++k) { int i = base + k; if (i < NBINS) s += counts[i]; }
    }
    sred[tid] = s;
    __syncthreads();
    for (int off = 128; off > 0; off >>= 1) {
        if (tid < off) sred[tid] += sred[tid + off];
        __syncthreads();
    }
    if (tid == 0) bsum[blockIdx.x] = sred[0];
}

__global__ __launch_bounds__(512) void scan_bsum(int* __restrict__ bsum)
{
    __shared__ int sScan[512];
    const int tid = threadIdx.x;
    int vIn = (tid < NSCAN) ? bsum[tid] : 0;
    sScan[tid] = vIn;
    __syncthreads();
    for (int off = 1; off < 512; off <<= 1) {
        int val = (tid >= off) ? sScan[tid - off] : 0;
        __syncthreads();
        sScan[tid] += val;
        __syncthreads();
    }
    if (tid < NSCAN) bsum[tid] = sScan[tid] - vIn;   // exclusive
}

__global__ __launch_bounds__(256) void scan_apply(int* __restrict__ counts,
                                                  const int* __restrict__ bsum)
{
    __shared__ int sScan[256];
    const int tid = threadIdx.x;
    int base = blockIdx.x * 1024 + tid * 4;
    int v0 = 0, v1 = 0, v2 = 0, v3 = 0;
    if (base + 3 < NBINS) {
        int4 c = *(const int4*)&counts[base];
        v0 = c.x; v1 = c.y; v2 = c.z; v3 = c.w;
    } else {
        if (base     < NBINS) v0 = counts[base];
        if (base + 1 < NBINS) v1 = counts[base + 1];
        if (base + 2 < NBINS) v2 = counts[base + 2];
        if (base + 3 < NBINS) v3 = counts[base + 3];
    }
    int tsum = v0 + v1 + v2 + v3;
    sScan[tid] = tsum;
    __syncthreads();
    for (int off = 1; off < 256; off <<= 1) {
        int val = (tid >= off) ? sScan[tid - off] : 0;
        __syncthreads();
        sScan[tid] += val;
        __syncthreads();
    }
    int excl = sScan[tid] - tsum + bsum[blockIdx.x];
    if (base     < NBINS) counts[base]     = excl;
    if (base + 1 < NBINS) counts[base + 1] = excl + v0;
    if (base + 2 < NBINS) counts[base + 2] = excl + v0 + v1;
    if (base + 3 < NBINS) counts[base + 3] = excl + v0 + v1 + v2;
}

// ---------------------------------------------------------------------------
// permute+gather: scatter edges into (bucket,iu)-sorted order, pre-gathering
// iuv packed indices + ev row as bf16.
// ---------------------------------------------------------------------------
__global__ __launch_bounds__(256) void permute_kernel(
    const int* __restrict__ idx_u, const int* __restrict__ idx_v,
    const float* __restrict__ ev, int* __restrict__ cursor,
    unsigned int* __restrict__ iuv_s, unsigned short* __restrict__ evs)
{
    int e = blockIdx.x * 256 + threadIdx.x;
    if (e >= E_N) return;
    int iu = idx_u[e];
    int iv = idx_v[e];
    int key = (iv >> VSHIFT) * U_N + iu;
    int pos = atomicAdd(&cursor[key], 1);
    iuv_s[pos] = (unsigned)iu | ((unsigned)iv << 16);

    const float* src = &ev[(size_t)e * 16];
    unsigned short* dst = &evs[(size_t)pos * 16];
#pragma unroll
    for (int q = 0; q < 4; ++q) {
        float4 a = *(const float4*)&src[q * 4];
        ushort4 o;
        o.x = f2bf(a.x); o.y = f2bf(a.y); o.z = f2bf(a.z); o.w = f2bf(a.w);
        *(ushort4*)&dst[q * 4] = o;
    }
}

// ---------------------------------------------------------------------------
// edge kernel over SORTED pre-gathered edges (byte-identical to R9's verified
// 140us version): 64 edges/block, 4 waves, wave-local rows, register-
// prefetched gathers. With bucketed sort, Vp reads fall in a 2.1 MB L2 slice.
// ---------------------------------------------------------------------------
__global__ __launch_bounds__(256, 5) void edge_kernel(
    const unsigned short* __restrict__ Up,   // 50000 x 128 bf16
    const unsigned short* __restrict__ Vp,   // 50000 x 128 bf16
    const unsigned short* __restrict__ evs,  // E x 16 bf16, sorted
    const unsigned int* __restrict__ iuv_s,  // E packed (iu | iv<<16), sorted
    const unsigned short* __restrict__ Wef,  // layer-1 A frags (We^T, K=32 pad)
    const float* __restrict__ gb1,
    const unsigned short* __restrict__ W2f,  // layer-2 B frags
    const float* __restrict__ gb2,
    float* __restrict__ agg)
{
    __shared__ unsigned short sH1[64 * 136];  // aliased as sH2 f32 [64][68]
    __shared__ int sIu[64];

    const int tid = threadIdx.x;
    const int e0 = blockIdx.x * 64;
    const int wid = tid >> 6, lane = tid & 63;
    const int lo = lane & 15, hi = lane >> 4;
    const int g = e0 + wid * 16 + lo;         // this lane's (sorted) edge

    const unsigned iuv = iuv_s[g];
    const int iu = (int)(iuv & 0xFFFFu);
    const int iv = (int)(iuv >> 16);
    if (hi == 0) sIu[wid * 16 + lo] = iu;     // wave-local write

    // ---- register-prefetch the gathers (16 independent 8B loads) ----
    ushort4 upv[8], vpv[8];
#pragma unroll
    for (int ct = 0; ct < 8; ++ct) {
        upv[ct] = *(const ushort4*)&Up[(size_t)iu * 128 + ct * 16 + hi * 4];
        vpv[ct] = *(const ushort4*)&Vp[(size_t)iv * 128 + ct * 16 + hi * 4];
    }

    // ---- layer 1 MFMA: B-frag = evs row (coalesced); A = Wef (L1-hot) ----
    bf16x8 bfrag;
    if (hi < 2) {
        bfrag = *(const bf16x8*)&evs[(size_t)g * 16 + hi * 8];
    } else {
        bfrag = (bf16x8)(short)0;             // K-pad 16->32
    }

    f32x4 acc[8];
#pragma unroll
    for (int ct = 0; ct < 8; ++ct) {
#pragma unroll
        for (int r = 0; r < 4; ++r) acc[ct][r] = 0.f;
        bf16x8 a = *(const bf16x8*)&Wef[(size_t)((ct * 64 + lane) * 8)];
        acc[ct] = __builtin_amdgcn_mfma_f32_16x16x32_bf16(a, bfrag, acc[ct], 0, 0, 0);
    }

    // epilogue: h1 = relu(acc + b1 + Up[iu] + Vp[iv]) -> bf16 LDS (wave-local)
    const int e_loc = wid * 16 + lo;
#pragma unroll
    for (int ct = 0; ct < 8; ++ct) {
        int c0 = ct * 16 + hi * 4;
        float4 b1 = *(const float4*)&gb1[c0];
        ushort4 uv = upv[ct], vv = vpv[ct];
        ushort4 h;
        h.x = f2bf(relu(acc[ct][0] + b1.x + bf2f(uv.x) + bf2f(vv.x)));
        h.y = f2bf(relu(acc[ct][1] + b1.y + bf2f(uv.y) + bf2f(vv.y)));
        h.z = f2bf(relu(acc[ct][2] + b1.z + bf2f(uv.z) + bf2f(vv.z)));
        h.w = f2bf(relu(acc[ct][3] + b1.w + bf2f(uv.w) + bf2f(vv.w)));
        *(ushort4*)&sH1[e_loc * 136 + c0] = h;
    }
    // intra-wave ushort write->read on same array: compiler-ordered, no barrier

    // ---- layer 2 via MFMA: wave reads its OWN 16 rows of sH1 ----
    f32x4 accm[4];
#pragma unroll
    for (int nt = 0; nt < 4; ++nt)
#pragma unroll
        for (int r = 0; r < 4; ++r) accm[nt][r] = 0.f;

#pragma unroll
    for (int ks = 0; ks < 4; ++ks) {
        bf16x8 a = *(const bf16x8*)&sH1[(wid * 16 + lo) * 136 + ks * 32 + hi * 8];
#pragma unroll
        for (int nt = 0; nt < 4; ++nt) {
            bf16x8 b = *(const bf16x8*)&W2f[(size_t)(((ks * 4 + nt) * 64 + lane) * 8)];
            accm[nt] = __builtin_amdgcn_mfma_f32_16x16x32_bf16(a, b, accm[nt], 0, 0, 0);
        }
    }
    __syncthreads();   // alias (ushort->float) boundary: all sH1 reads done

    float* sH2 = (float*)sH1;   // [64][68] fp32; wave-local byte range coincides
#pragma unroll
    for (int nt = 0; nt < 4; ++nt) {
        int col = nt * 16 + lo;
        float b2v = gb2[col];
        int erow = wid * 16 + hi * 4;
#pragma unroll
        for (int r = 0; r < 4; ++r)
            sH2[(erow + r) * 68 + col] = relu(accm[nt][r] + b2v);
    }
    // reduction reads own wave's rows (float->float, intra-wave): no barrier

    // ---- segmented reduction over sorted iu: thread = (col, own wave) ----
    {
        const int c = tid & 63;       // output column
        const int eq0 = wid * 16;     // this wave's 16 edges
        int   iu_cur = sIu[eq0];
        float running = 0.f;
#pragma unroll
        for (int k = 0; k < 16; ++k) {
            int e = eq0 + k;
            int iu2 = sIu[e];
            if (iu2 != iu_cur) {
                atomicAdd(&agg[(size_t)iu_cur * 64 + c], running);
                running = 0.f;
                iu_cur = iu2;
            }
            running += sH2[e * 68 + c];
        }
        atomicAdd(&agg[(size_t)iu_cur * 64 + c], running);
    }
}

// ---------------------------------------------------------------------------
// node kernel via MFMA: out = relu(relu([u,agg] @ fw1 + fb1) @ fw2 + fb2)
// ---------------------------------------------------------------------------
__global__ __launch_bounds__(256) void node_kernel(
    const float* __restrict__ u, const float* __restrict__ agg,
    const unsigned short* __restrict__ F1f, const float* __restrict__ fb1,
    const unsigned short* __restrict__ F2f, const float* __restrict__ fb2,
    float* __restrict__ out, int N)
{
    __shared__ unsigned short sY[64 * 136];   // y bf16, wave-local rows
    const int tid = threadIdx.x;
    const int wid = tid >> 6, lane = tid & 63;
    const int lo = lane & 15, hi = lane >> 4;
    const int row0 = blockIdx.x * 64;
    const int row = row0 + wid * 16 + lo;
    const int rl = (row < N) ? row : (N - 1);

    bf16x8 a0, a1, a2, a3;
    {
        union { bf16x8 v; unsigned short s[8]; } r0_, r1_, r2_, r3_;
        float4 x0 = *(const float4*)&u[(size_t)rl * 64 + hi * 8];
        float4 x1 = *(const float4*)&u[(size_t)rl * 64 + hi * 8 + 4];
        float4 x2 = *(const float4*)&u[(size_t)rl * 64 + 32 + hi * 8];
        float4 x3 = *(const float4*)&u[(size_t)rl * 64 + 32 + hi * 8 + 4];
        float4 g0 = *(const float4*)&agg[(size_t)rl * 64 + hi * 8];
        float4 g1 = *(const float4*)&agg[(size_t)rl * 64 + hi * 8 + 4];
        float4 g2 = *(const float4*)&agg[(size_t)rl * 64 + 32 + hi * 8];
        float4 g3 = *(const float4*)&agg[(size_t)rl * 64 + 32 + hi * 8 + 4];
        r0_.s[0] = f2bf(x0.x); r0_.s[1] = f2bf(x0.y); r0_.s[2] = f2bf(x0.z); r0_.s[3] = f2bf(x0.w);
        r0_.s[4] = f2bf(x1.x); r0_.s[5] = f2bf(x1.y); r0_.s[6] = f2bf(x1.z); r0_.s[7] = f2bf(x1.w);
        r1_.s[0] = f2bf(x2.x); r1_.s[1] = f2bf(x2.y); r1_.s[2] = f2bf(x2.z); r1_.s[3] = f2bf(x2.w);
        r1_.s[4] = f2bf(x3.x); r1_.s[5] = f2bf(x3.y); r1_.s[6] = f2bf(x3.z); r1_.s[7] = f2bf(x3.w);
        r2_.s[0] = f2bf(g0.x); r2_.s[1] = f2bf(g0.y); r2_.s[2] = f2bf(g0.z); r2_.s[3] = f2bf(g0.w);
        r2_.s[4] = f2bf(g1.x); r2_.s[5] = f2bf(g1.y); r2_.s[6] = f2bf(g1.z); r2_.s[7] = f2bf(g1.w);
        r3_.s[0] = f2bf(g2.x); r3_.s[1] = f2bf(g2.y); r3_.s[2] = f2bf(g2.z); r3_.s[3] = f2bf(g2.w);
        r3_.s[4] = f2bf(g3.x); r3_.s[5] = f2bf(g3.y); r3_.s[6] = f2bf(g3.z); r3_.s[7] = f2bf(g3.w);
        a0 = r0_.v; a1 = r1_.v; a2 = r2_.v; a3 = r3_.v;
    }

    // ---- layer 1: y = relu(x @ fw1 + fb1), 32 MFMAs/wave ----
#pragma unroll
    for (int nt = 0; nt < 8; ++nt) {
        f32x4 acc;
#pragma unroll
        for (int r = 0; r < 4; ++r) acc[r] = 0.f;
        bf16x8 b0 = *(const bf16x8*)&F1f[(size_t)(((0 * 8 + nt) * 64 + lane) * 8)];
        bf16x8 b1 = *(const bf16x8*)&F1f[(size_t)(((1 * 8 + nt) * 64 + lane) * 8)];
        bf16x8 b2 = *(const bf16x8*)&F1f[(size_t)(((2 * 8 + nt) * 64 + lane) * 8)];
        bf16x8 b3 = *(const bf16x8*)&F1f[(size_t)(((3 * 8 + nt) * 64 + lane) * 8)];
        acc = __builtin_amdgcn_mfma_f32_16x16x32_bf16(a0, b0, acc, 0, 0, 0);
        acc = __builtin_amdgcn_mfma_f32_16x16x32_bf16(a1, b1, acc, 0, 0, 0);
        acc = __builtin_amdgcn_mfma_f32_16x16x32_bf16(a2, b2, acc, 0, 0, 0);
        acc = __builtin_amdgcn_mfma_f32_16x16x32_bf16(a3, b3, acc, 0, 0, 0);
        int col = nt * 16 + lo;
        float b1v = fb1[col];
        int rbase = wid * 16 + hi * 4;
#pragma unroll
        for (int r = 0; r < 4; ++r)
            sY[(rbase + r) * 136 + col] = f2bf(relu(acc[r] + b1v));
    }

    // ---- layer 2: out = relu(y @ fw2 + fb2), 16 MFMAs/wave ----
    bf16x8 ya0 = *(const bf16x8*)&sY[(wid * 16 + lo) * 136 + 0 * 32 + hi * 8];
    bf16x8 ya1 = *(const bf16x8*)&sY[(wid * 16 + lo) * 136 + 1 * 32 + hi * 8];
    bf16x8 ya2 = *(const bf16x8*)&sY[(wid * 16 + lo) * 136 + 2 * 32 + hi * 8];
    bf16x8 ya3 = *(const bf16x8*)&sY[(wid * 16 + lo) * 136 + 3 * 32 + hi * 8];
#pragma unroll
    for (int nt = 0; nt < 4; ++nt) {
        f32x4 acc;
#pragma unroll
        for (int r = 0; r < 4; ++r) acc[r] = 0.f;
        bf16x8 b0 = *(const bf16x8*)&F2f[(size_t)(((0 * 4 + nt) * 64 + lane) * 8)];
        bf16x8 b1 = *(const bf16x8*)&F2f[(size_t)(((1 * 4 + nt) * 64 + lane) * 8)];
        bf16x8 b2 = *(const bf16x8*)&F2f[(size_t)(((2 * 4 + nt) * 64 + lane) * 8)];
        bf16x8 b3 = *(const bf16x8*)&F2f[(size_t)(((3 * 4 + nt) * 64 + lane) * 8)];
        acc = __builtin_amdgcn_mfma_f32_16x16x32_bf16(ya0, b0, acc, 0, 0, 0);
        acc = __builtin_amdgcn_mfma_f32_16x16x32_bf16(ya1, b1, acc, 0, 0, 0);
        acc = __builtin_amdgcn_mfma_f32_16x16x32_bf16(ya2, b2, acc, 0, 0, 0);
        acc = __builtin_amdgcn_mfma_f32_16x16x32_bf16(ya3, b3, acc, 0, 0, 0);
        int col = nt * 16 + lo;
        float b2v = fb2[col];
#pragma unroll
        for (int r = 0; r < 4; ++r) {
            int gr = row0 + wid * 16 + hi * 4 + r;
            if (gr < N) out[(size_t)gr * 64 + col] = relu(acc[r] + b2v);
        }
    }
}

// ---------------------------------------------------------------------------
extern "C" void kernel_launch(void* const* d_in, const int* in_sizes, int n_in,
                              void* d_out, int out_size, void* d_ws, size_t ws_size,
                              hipStream_t stream)
{
    const float* u   = (const float*)d_in[0];
    const float* v   = (const float*)d_in[1];
    const float* ev  = (const float*)d_in[2];
    const int*   eiv = (const int*)d_in[3];
    const int*   eiu = (const int*)d_in[4];
    const float* gw1 = (const float*)d_in[5];   // 144 x 128
    const float* gb1 = (const float*)d_in[6];   // 128
    const float* gw2 = (const float*)d_in[7];   // 128 x 64
    const float* gb2 = (const float*)d_in[8];   // 64
    const float* fw1 = (const float*)d_in[9];   // 128 x 128
    const float* fb1 = (const float*)d_in[10];  // 128
    const float* fw2 = (const float*)d_in[11];  // 128 x 64
    const float* fb2 = (const float*)d_in[12];  // 64
    float* out = (float*)d_out;

    // workspace layout (agg and counts adjacent -> single memset); ~68.7 MB
    unsigned short* Up     = (unsigned short*)d_ws;                 // 50000x128 bf16
    unsigned short* Vp     = Up + (size_t)U_N * 128;                // 50000x128 bf16
    unsigned short* evs    = Vp + (size_t)V_N * 128;                // E x 16 bf16
    float*          agg    = (float*)(evs + (size_t)E_N * 16);      // 50000x64 f32
    int*            counts = (int*)(agg + (size_t)U_N * 64);        // NBINS (= cursor)
    unsigned int*   iuv_s  = (unsigned int*)(counts + NBINS);       // 800000
    unsigned short* W2f    = (unsigned short*)(iuv_s + E_N);        // 8192 bf16
    unsigned short* Wef    = W2f + 8192;                            // 4096 bf16
    unsigned short* F1f    = Wef + 4096;                            // 16384 bf16
    unsigned short* F2f    = F1f + 16384;                           // 8192 bf16
    int*            bsum   = (int*)(F2f + 8192);                    // NSCAN ints

    // one memset covers agg (zero init) + counts (hist init)
    hipMemsetAsync(agg, 0, ((size_t)U_N * 64 + NBINS) * sizeof(float), stream);

    dim3 blk(256);
    prep_kernel<<<dim3(2 * NB_PROJ + 1 + NB_HIST), blk, 0, stream>>>(
        eiu, eiv, counts, u, v, gw1, gw2, fw1, fw2, Up, Vp, W2f, Wef, F1f, F2f);
    scan_sums<<<dim3(NSCAN), blk, 0, stream>>>(counts, bsum);
    scan_bsum<<<dim3(1), dim3(512), 0, stream>>>(bsum);
    scan_apply<<<dim3(NSCAN), blk, 0, stream>>>(counts, bsum);
    permute_kernel<<<dim3(NB_HIST), blk, 0, stream>>>(
        eiu, eiv, ev, counts, iuv_s, evs);

    edge_kernel<<<dim3(E_N / 64), blk, 0, stream>>>(
        Up, Vp, evs, iuv_s, Wef, gb1, W2f, gb2, agg);
    node_kernel<<<dim3((U_N + 63) / 64), blk, 0, stream>>>(
        u, agg, F1f, fb1, F2f, fb2, out, U_N);
}

// Round 12
// 265.663 us; speedup vs baseline: 2.8760x; 1.0431x over previous
//
#include <hip/hip_runtime.h>

// Problem constants (match reference)
constexpr int U_N = 50000;
constexpr int V_N = 50000;
constexpr int E_N = 800000;   // == 64 * 12500
// dims: F=64, G=64, H=16; g: 144->128->64; f: 128->128->64

typedef float f32x4 __attribute__((ext_vector_type(4)));
typedef short bf16x8 __attribute__((ext_vector_type(8)));

__device__ __forceinline__ float relu(float x) { return fmaxf(x, 0.f); }

// round-to-nearest-even fp32 -> bf16 bits
__device__ __forceinline__ unsigned short f2bf(float f) {
    unsigned u = __float_as_uint(f);
    unsigned rounding = 0x7FFFu + ((u >> 16) & 1u);
    return (unsigned short)((u + rounding) >> 16);
}
__device__ __forceinline__ float bf2f(unsigned short b) {
    return __uint_as_float(((unsigned)b) << 16);
}

constexpr int NB_HIST = (E_N + 255) / 256;   // 3125
constexpr int NB_PROJ = (U_N + 63) / 64;     // 782

// Sort key = iu (bucketing by iv refuted in R11: atomic-run splitting cost
// more than Vp L2-residency gained). Multi-block scan kept (R11's real win).
constexpr int NBINS = U_N;                   // 50000
constexpr int NSCAN = (NBINS + 1023) / 1024; // 49

// ---------------------------------------------------------------------------
// proj via MFMA: P[row0..row0+64][128] = bf16(X[.][64]) @ bf16(W[64][128])
// ---------------------------------------------------------------------------
__device__ __forceinline__ void proj_mfma(const float* __restrict__ X,
                                          const float* __restrict__ W,  // 64x128
                                          unsigned short* __restrict__ P,
                                          int N, int row0,
                                          unsigned short* sWf)
{
    const int tid = threadIdx.x;

    for (int idx = tid; idx < 64 * 128 / 4; idx += 256) {
        int k  = (idx * 4) >> 7;
        int n0 = (idx * 4) & 127;
        float4 w = *(const float4*)&W[k * 128 + n0];
        int ks = k >> 5, hi = (k & 31) >> 3, j = k & 7;
        float wv[4] = {w.x, w.y, w.z, w.w};
#pragma unroll
        for (int q = 0; q < 4; ++q) {
            int n = n0 + q, nt = n >> 4, lo = n & 15;
            sWf[((ks * 8 + nt) * 64 + hi * 16 + lo) * 8 + j] = f2bf(wv[q]);
        }
    }
    __syncthreads();

    const int wid = tid >> 6, lane = tid & 63;
    const int lo = lane & 15, hi = lane >> 4;
    const int row = row0 + wid * 16 + lo;
    const int rl = (row < N) ? row : (N - 1);

    bf16x8 a0, a1;
    {
        union { bf16x8 v; unsigned short s[8]; } ra, rb;
        float4 x0 = *(const float4*)&X[(size_t)rl * 64 + hi * 8];
        float4 x1 = *(const float4*)&X[(size_t)rl * 64 + hi * 8 + 4];
        ra.s[0] = f2bf(x0.x); ra.s[1] = f2bf(x0.y); ra.s[2] = f2bf(x0.z); ra.s[3] = f2bf(x0.w);
        ra.s[4] = f2bf(x1.x); ra.s[5] = f2bf(x1.y); ra.s[6] = f2bf(x1.z); ra.s[7] = f2bf(x1.w);
        float4 y0 = *(const float4*)&X[(size_t)rl * 64 + 32 + hi * 8];
        float4 y1 = *(const float4*)&X[(size_t)rl * 64 + 32 + hi * 8 + 4];
        rb.s[0] = f2bf(y0.x); rb.s[1] = f2bf(y0.y); rb.s[2] = f2bf(y0.z); rb.s[3] = f2bf(y0.w);
        rb.s[4] = f2bf(y1.x); rb.s[5] = f2bf(y1.y); rb.s[6] = f2bf(y1.z); rb.s[7] = f2bf(y1.w);
        a0 = ra.v; a1 = rb.v;
    }

    const int rbase = row0 + wid * 16 + hi * 4;
#pragma unroll
    for (int nt = 0; nt < 8; ++nt) {
        f32x4 acc;
#pragma unroll
        for (int r = 0; r < 4; ++r) acc[r] = 0.f;
        bf16x8 b0 = *(const bf16x8*)&sWf[((0 * 8 + nt) * 64 + lane) * 8];
        bf16x8 b1 = *(const bf16x8*)&sWf[((1 * 8 + nt) * 64 + lane) * 8];
        acc = __builtin_amdgcn_mfma_f32_16x16x32_bf16(a0, b0, acc, 0, 0, 0);
        acc = __builtin_amdgcn_mfma_f32_16x16x32_bf16(a1, b1, acc, 0, 0, 0);
#pragma unroll
        for (int r = 0; r < 4; ++r) {
            int gr = rbase + r;
            if (gr < N) P[(size_t)gr * 128 + nt * 16 + lo] = f2bf(acc[r]);
        }
    }
}

// ---------------------------------------------------------------------------
// prep kernel: projU (MFMA), projV (MFMA), weight-pack, histogram.
// ---------------------------------------------------------------------------
__global__ __launch_bounds__(256) void prep_kernel(
    const int* __restrict__ idx_u, int* __restrict__ counts,
    const float* __restrict__ u, const float* __restrict__ v,
    const float* __restrict__ gw1, const float* __restrict__ gw2,
    const float* __restrict__ fw1, const float* __restrict__ fw2,
    unsigned short* __restrict__ Up, unsigned short* __restrict__ Vp,
    unsigned short* __restrict__ W2f, unsigned short* __restrict__ Wef,
    unsigned short* __restrict__ F1f, unsigned short* __restrict__ F2f)
{
    __shared__ unsigned short sWf[8192];   // proj branches only
    int b = blockIdx.x;

    if (b < NB_PROJ) {
        proj_mfma(u, gw1, Up, U_N, b * 64, sWf);
        return;
    }
    b -= NB_PROJ;
    if (b < NB_PROJ) {
        proj_mfma(v, gw1 + 64 * 128, Vp, V_N, b * 64, sWf);
        return;
    }
    b -= NB_PROJ;
    if (b == 0) {
        const int tid = threadIdx.x;
        // W2f (edge L2, gw2 128x64) and F2f (node L2, fw2 128x64): same layout
        for (int t = tid; t < 4 * 4 * 64 * 8; t += 256) {
            int j    = t & 7;
            int lane = (t >> 3) & 63;
            int nt   = (t >> 9) & 3;
            int ks   = t >> 11;
            int n = nt * 16 + (lane & 15);
            int k = ks * 32 + (lane >> 4) * 8 + j;
            W2f[t] = f2bf(gw2[k * 64 + n]);
            F2f[t] = f2bf(fw2[k * 64 + n]);
        }
        // Wef (edge L1 A-frags, We^T, K padded to 32)
        const float* gw1e = gw1 + 128 * 128;   // 16 x 128
        for (int t = tid; t < 8 * 64 * 8; t += 256) {
            int j    = t & 7;
            int lane = (t >> 3) & 63;
            int ct   = t >> 9;
            int c = ct * 16 + (lane & 15);
            int k = (lane >> 4) * 8 + j;
            Wef[t] = (k < 16) ? f2bf(gw1e[k * 128 + c]) : (unsigned short)0;
        }
        // F1f (node L1, fw1 128x128): ks 0..3, nt 0..7
        for (int t = tid; t < 4 * 8 * 64 * 8; t += 256) {
            int j    = t & 7;
            int lane = (t >> 3) & 63;
            int nt   = (t >> 9) & 7;
            int ks   = t >> 12;
            int n = nt * 16 + (lane & 15);
            int k = ks * 32 + (lane >> 4) * 8 + j;
            F1f[t] = f2bf(fw1[k * 128 + n]);
        }
        return;
    }
    b -= 1;
    // ---- histogram (key = iu) ----
    int e = b * 256 + threadIdx.x;
    if (e < E_N) atomicAdd(&counts[idx_u[e]], 1);
}

// ---------------------------------------------------------------------------
// multi-block exclusive scan of counts[0..NBINS): sums -> scan sums -> apply
// ---------------------------------------------------------------------------
__global__ __launch_bounds__(256) void scan_sums(const int* __restrict__ counts,
                                                 int* __restrict__ bsum)
{
    __shared__ int sred[256];
    const int tid = threadIdx.x;
    int base = blockIdx.x * 1024 + tid * 4;
    int s = 0;
    if (base + 3 < NBINS) {
        int4 c = *(const int4*)&counts[base];
        s = c.x + c.y + c.z + c.w;
    } else {
#pragma unroll
        for (int k = 0; k < 4; ++k) { int i = base + k; if (i < NBINS) s += counts[i]; }
    }
    sred[tid] = s;
    __syncthreads();
    for (int off = 128; off > 0; off >>= 1) {
        if (tid < off) sred[tid] += sred[tid + off];
        __syncthreads();
    }
    if (tid == 0) bsum[blockIdx.x] = sred[0];
}

__global__ __launch_bounds__(512) void scan_bsum(int* __restrict__ bsum)
{
    __shared__ int sScan[512];
    const int tid = threadIdx.x;
    int vIn = (tid < NSCAN) ? bsum[tid] : 0;
    sScan[tid] = vIn;
    __syncthreads();
    for (int off = 1; off < 512; off <<= 1) {
        int val = (tid >= off) ? sScan[tid - off] : 0;
        __syncthreads();
        sScan[tid] += val;
        __syncthreads();
    }
    if (tid < NSCAN) bsum[tid] = sScan[tid] - vIn;   // exclusive
}

__global__ __launch_bounds__(256) void scan_apply(int* __restrict__ counts,
                                                  const int* __restrict__ bsum)
{
    __shared__ int sScan[256];
    const int tid = threadIdx.x;
    int base = blockIdx.x * 1024 + tid * 4;
    int v0 = 0, v1 = 0, v2 = 0, v3 = 0;
    if (base + 3 < NBINS) {
        int4 c = *(const int4*)&counts[base];
        v0 = c.x; v1 = c.y; v2 = c.z; v3 = c.w;
    } else {
        if (base     < NBINS) v0 = counts[base];
        if (base + 1 < NBINS) v1 = counts[base + 1];
        if (base + 2 < NBINS) v2 = counts[base + 2];
        if (base + 3 < NBINS) v3 = counts[base + 3];
    }
    int tsum = v0 + v1 + v2 + v3;
    sScan[tid] = tsum;
    __syncthreads();
    for (int off = 1; off < 256; off <<= 1) {
        int val = (tid >= off) ? sScan[tid - off] : 0;
        __syncthreads();
        sScan[tid] += val;
        __syncthreads();
    }
    int excl = sScan[tid] - tsum + bsum[blockIdx.x];
    if (base     < NBINS) counts[base]     = excl;
    if (base + 1 < NBINS) counts[base + 1] = excl + v0;
    if (base + 2 < NBINS) counts[base + 2] = excl + v0 + v1;
    if (base + 3 < NBINS) counts[base + 3] = excl + v0 + v1 + v2;
}

// ---------------------------------------------------------------------------
// permute+gather: scatter edges into iu-sorted order, pre-gathering
// iuv packed indices + ev row as bf16.
// ---------------------------------------------------------------------------
__global__ __launch_bounds__(256) void permute_kernel(
    const int* __restrict__ idx_u, const int* __restrict__ idx_v,
    const float* __restrict__ ev, int* __restrict__ cursor,
    unsigned int* __restrict__ iuv_s, unsigned short* __restrict__ evs)
{
    int e = blockIdx.x * 256 + threadIdx.x;
    if (e >= E_N) return;
    int iu = idx_u[e];
    int iv = idx_v[e];
    int pos = atomicAdd(&cursor[iu], 1);
    iuv_s[pos] = (unsigned)iu | ((unsigned)iv << 16);

    const float* src = &ev[(size_t)e * 16];
    unsigned short* dst = &evs[(size_t)pos * 16];
#pragma unroll
    for (int q = 0; q < 4; ++q) {
        float4 a = *(const float4*)&src[q * 4];
        ushort4 o;
        o.x = f2bf(a.x); o.y = f2bf(a.y); o.z = f2bf(a.z); o.w = f2bf(a.w);
        *(ushort4*)&dst[q * 4] = o;
    }
}

// ---------------------------------------------------------------------------
// edge kernel over SORTED pre-gathered edges (R9's verified structure) at
// 8 blocks/CU: VGPR 44 <= 64, LDS 17.9KB*8 = 143KB <= 160KB. Latency-bound
// with all pipes idle -> raise waves in flight 20 -> 32 per CU.
// ---------------------------------------------------------------------------
__global__ __launch_bounds__(256, 8) void edge_kernel(
    const unsigned short* __restrict__ Up,   // 50000 x 128 bf16
    const unsigned short* __restrict__ Vp,   // 50000 x 128 bf16
    const unsigned short* __restrict__ evs,  // E x 16 bf16, sorted
    const unsigned int* __restrict__ iuv_s,  // E packed (iu | iv<<16), sorted
    const unsigned short* __restrict__ Wef,  // layer-1 A frags (We^T, K=32 pad)
    const float* __restrict__ gb1,
    const unsigned short* __restrict__ W2f,  // layer-2 B frags
    const float* __restrict__ gb2,
    float* __restrict__ agg)
{
    __shared__ unsigned short sH1[64 * 136];  // aliased as sH2 f32 [64][68]
    __shared__ int sIu[64];

    const int tid = threadIdx.x;
    const int e0 = blockIdx.x * 64;
    const int wid = tid >> 6, lane = tid & 63;
    const int lo = lane & 15, hi = lane >> 4;
    const int g = e0 + wid * 16 + lo;         // this lane's (sorted) edge

    const unsigned iuv = iuv_s[g];
    const int iu = (int)(iuv & 0xFFFFu);
    const int iv = (int)(iuv >> 16);
    if (hi == 0) sIu[wid * 16 + lo] = iu;     // wave-local write

    // ---- register-prefetch the gathers (16 independent 8B loads) ----
    ushort4 upv[8], vpv[8];
#pragma unroll
    for (int ct = 0; ct < 8; ++ct) {
        upv[ct] = *(const ushort4*)&Up[(size_t)iu * 128 + ct * 16 + hi * 4];
        vpv[ct] = *(const ushort4*)&Vp[(size_t)iv * 128 + ct * 16 + hi * 4];
    }

    // ---- layer 1 MFMA: B-frag = evs row (coalesced); A = Wef (L1-hot) ----
    bf16x8 bfrag;
    if (hi < 2) {
        bfrag = *(const bf16x8*)&evs[(size_t)g * 16 + hi * 8];
    } else {
        bfrag = (bf16x8)(short)0;             // K-pad 16->32
    }

    f32x4 acc[8];
#pragma unroll
    for (int ct = 0; ct < 8; ++ct) {
#pragma unroll
        for (int r = 0; r < 4; ++r) acc[ct][r] = 0.f;
        bf16x8 a = *(const bf16x8*)&Wef[(size_t)((ct * 64 + lane) * 8)];
        acc[ct] = __builtin_amdgcn_mfma_f32_16x16x32_bf16(a, bfrag, acc[ct], 0, 0, 0);
    }

    // epilogue: h1 = relu(acc + b1 + Up[iu] + Vp[iv]) -> bf16 LDS (wave-local)
    const int e_loc = wid * 16 + lo;
#pragma unroll
    for (int ct = 0; ct < 8; ++ct) {
        int c0 = ct * 16 + hi * 4;
        float4 b1 = *(const float4*)&gb1[c0];
        ushort4 uv = upv[ct], vv = vpv[ct];
        ushort4 h;
        h.x = f2bf(relu(acc[ct][0] + b1.x + bf2f(uv.x) + bf2f(vv.x)));
        h.y = f2bf(relu(acc[ct][1] + b1.y + bf2f(uv.y) + bf2f(vv.y)));
        h.z = f2bf(relu(acc[ct][2] + b1.z + bf2f(uv.z) + bf2f(vv.z)));
        h.w = f2bf(relu(acc[ct][3] + b1.w + bf2f(uv.w) + bf2f(vv.w)));
        *(ushort4*)&sH1[e_loc * 136 + c0] = h;
    }
    // intra-wave ushort write->read on same array: compiler-ordered, no barrier

    // ---- layer 2 via MFMA: wave reads its OWN 16 rows of sH1 ----
    f32x4 accm[4];
#pragma unroll
    for (int nt = 0; nt < 4; ++nt)
#pragma unroll
        for (int r = 0; r < 4; ++r) accm[nt][r] = 0.f;

#pragma unroll
    for (int ks = 0; ks < 4; ++ks) {
        bf16x8 a = *(const bf16x8*)&sH1[(wid * 16 + lo) * 136 + ks * 32 + hi * 8];
#pragma unroll
        for (int nt = 0; nt < 4; ++nt) {
            bf16x8 b = *(const bf16x8*)&W2f[(size_t)(((ks * 4 + nt) * 64 + lane) * 8)];
            accm[nt] = __builtin_amdgcn_mfma_f32_16x16x32_bf16(a, b, accm[nt], 0, 0, 0);
        }
    }
    __syncthreads();   // alias (ushort->float) boundary: all sH1 reads done

    float* sH2 = (float*)sH1;   // [64][68] fp32; wave-local byte range coincides
#pragma unroll
    for (int nt = 0; nt < 4; ++nt) {
        int col = nt * 16 + lo;
        float b2v = gb2[col];
        int erow = wid * 16 + hi * 4;
#pragma unroll
        for (int r = 0; r < 4; ++r)
            sH2[(erow + r) * 68 + col] = relu(accm[nt][r] + b2v);
    }
    // reduction reads own wave's rows (float->float, intra-wave): no barrier

    // ---- segmented reduction over sorted iu: thread = (col, own wave) ----
    {
        const int c = tid & 63;       // output column
        const int eq0 = wid * 16;     // this wave's 16 edges
        int   iu_cur = sIu[eq0];
        float running = 0.f;
#pragma unroll
        for (int k = 0; k < 16; ++k) {
            int e = eq0 + k;
            int iu2 = sIu[e];
            if (iu2 != iu_cur) {
                atomicAdd(&agg[(size_t)iu_cur * 64 + c], running);
                running = 0.f;
                iu_cur = iu2;
            }
            running += sH2[e * 68 + c];
        }
        atomicAdd(&agg[(size_t)iu_cur * 64 + c], running);
    }
}

// ---------------------------------------------------------------------------
// node kernel via MFMA: out = relu(relu([u,agg] @ fw1 + fb1) @ fw2 + fb2)
// ---------------------------------------------------------------------------
__global__ __launch_bounds__(256) void node_kernel(
    const float* __restrict__ u, const float* __restrict__ agg,
    const unsigned short* __restrict__ F1f, const float* __restrict__ fb1,
    const unsigned short* __restrict__ F2f, const float* __restrict__ fb2,
    float* __restrict__ out, int N)
{
    __shared__ unsigned short sY[64 * 136];   // y bf16, wave-local rows
    const int tid = threadIdx.x;
    const int wid = tid >> 6, lane = tid & 63;
    const int lo = lane & 15, hi = lane >> 4;
    const int row0 = blockIdx.x * 64;
    const int row = row0 + wid * 16 + lo;
    const int rl = (row < N) ? row : (N - 1);

    bf16x8 a0, a1, a2, a3;
    {
        union { bf16x8 v; unsigned short s[8]; } r0_, r1_, r2_, r3_;
        float4 x0 = *(const float4*)&u[(size_t)rl * 64 + hi * 8];
        float4 x1 = *(const float4*)&u[(size_t)rl * 64 + hi * 8 + 4];
        float4 x2 = *(const float4*)&u[(size_t)rl * 64 + 32 + hi * 8];
        float4 x3 = *(const float4*)&u[(size_t)rl * 64 + 32 + hi * 8 + 4];
        float4 g0 = *(const float4*)&agg[(size_t)rl * 64 + hi * 8];
        float4 g1 = *(const float4*)&agg[(size_t)rl * 64 + hi * 8 + 4];
        float4 g2 = *(const float4*)&agg[(size_t)rl * 64 + 32 + hi * 8];
        float4 g3 = *(const float4*)&agg[(size_t)rl * 64 + 32 + hi * 8 + 4];
        r0_.s[0] = f2bf(x0.x); r0_.s[1] = f2bf(x0.y); r0_.s[2] = f2bf(x0.z); r0_.s[3] = f2bf(x0.w);
        r0_.s[4] = f2bf(x1.x); r0_.s[5] = f2bf(x1.y); r0_.s[6] = f2bf(x1.z); r0_.s[7] = f2bf(x1.w);
        r1_.s[0] = f2bf(x2.x); r1_.s[1] = f2bf(x2.y); r1_.s[2] = f2bf(x2.z); r1_.s[3] = f2bf(x2.w);
        r1_.s[4] = f2bf(x3.x); r1_.s[5] = f2bf(x3.y); r1_.s[6] = f2bf(x3.z); r1_.s[7] = f2bf(x3.w);
        r2_.s[0] = f2bf(g0.x); r2_.s[1] = f2bf(g0.y); r2_.s[2] = f2bf(g0.z); r2_.s[3] = f2bf(g0.w);
        r2_.s[4] = f2bf(g1.x); r2_.s[5] = f2bf(g1.y); r2_.s[6] = f2bf(g1.z); r2_.s[7] = f2bf(g1.w);
        r3_.s[0] = f2bf(g2.x); r3_.s[1] = f2bf(g2.y); r3_.s[2] = f2bf(g2.z); r3_.s[3] = f2bf(g2.w);
        r3_.s[4] = f2bf(g3.x); r3_.s[5] = f2bf(g3.y); r3_.s[6] = f2bf(g3.z); r3_.s[7] = f2bf(g3.w);
        a0 = r0_.v; a1 = r1_.v; a2 = r2_.v; a3 = r3_.v;
    }

    // ---- layer 1: y = relu(x @ fw1 + fb1), 32 MFMAs/wave ----
#pragma unroll
    for (int nt = 0; nt < 8; ++nt) {
        f32x4 acc;
#pragma unroll
        for (int r = 0; r < 4; ++r) acc[r] = 0.f;
        bf16x8 b0 = *(const bf16x8*)&F1f[(size_t)(((0 * 8 + nt) * 64 + lane) * 8)];
        bf16x8 b1 = *(const bf16x8*)&F1f[(size_t)(((1 * 8 + nt) * 64 + lane) * 8)];
        bf16x8 b2 = *(const bf16x8*)&F1f[(size_t)(((2 * 8 + nt) * 64 + lane) * 8)];
        bf16x8 b3 = *(const bf16x8*)&F1f[(size_t)(((3 * 8 + nt) * 64 + lane) * 8)];
        acc = __builtin_amdgcn_mfma_f32_16x16x32_bf16(a0, b0, acc, 0, 0, 0);
        acc = __builtin_amdgcn_mfma_f32_16x16x32_bf16(a1, b1, acc, 0, 0, 0);
        acc = __builtin_amdgcn_mfma_f32_16x16x32_bf16(a2, b2, acc, 0, 0, 0);
        acc = __builtin_amdgcn_mfma_f32_16x16x32_bf16(a3, b3, acc, 0, 0, 0);
        int col = nt * 16 + lo;
        float b1v = fb1[col];
        int rbase = wid * 16 + hi * 4;
#pragma unroll
        for (int r = 0; r < 4; ++r)
            sY[(rbase + r) * 136 + col] = f2bf(relu(acc[r] + b1v));
    }

    // ---- layer 2: out = relu(y @ fw2 + fb2), 16 MFMAs/wave ----
    bf16x8 ya0 = *(const bf16x8*)&sY[(wid * 16 + lo) * 136 + 0 * 32 + hi * 8];
    bf16x8 ya1 = *(const bf16x8*)&sY[(wid * 16 + lo) * 136 + 1 * 32 + hi * 8];
    bf16x8 ya2 = *(const bf16x8*)&sY[(wid * 16 + lo) * 136 + 2 * 32 + hi * 8];
    bf16x8 ya3 = *(const bf16x8*)&sY[(wid * 16 + lo) * 136 + 3 * 32 + hi * 8];
#pragma unroll
    for (int nt = 0; nt < 4; ++nt) {
        f32x4 acc;
#pragma unroll
        for (int r = 0; r < 4; ++r) acc[r] = 0.f;
        bf16x8 b0 = *(const bf16x8*)&F2f[(size_t)(((0 * 4 + nt) * 64 + lane) * 8)];
        bf16x8 b1 = *(const bf16x8*)&F2f[(size_t)(((1 * 4 + nt) * 64 + lane) * 8)];
        bf16x8 b2 = *(const bf16x8*)&F2f[(size_t)(((2 * 4 + nt) * 64 + lane) * 8)];
        bf16x8 b3 = *(const bf16x8*)&F2f[(size_t)(((3 * 4 + nt) * 64 + lane) * 8)];
        acc = __builtin_amdgcn_mfma_f32_16x16x32_bf16(ya0, b0, acc, 0, 0, 0);
        acc = __builtin_amdgcn_mfma_f32_16x16x32_bf16(ya1, b1, acc, 0, 0, 0);
        acc = __builtin_amdgcn_mfma_f32_16x16x32_bf16(ya2, b2, acc, 0, 0, 0);
        acc = __builtin_amdgcn_mfma_f32_16x16x32_bf16(ya3, b3, acc, 0, 0, 0);
        int col = nt * 16 + lo;
        float b2v = fb2[col];
#pragma unroll
        for (int r = 0; r < 4; ++r) {
            int gr = row0 + wid * 16 + hi * 4 + r;
            if (gr < N) out[(size_t)gr * 64 + col] = relu(acc[r] + b2v);
        }
    }
}

// ---------------------------------------------------------------------------
extern "C" void kernel_launch(void* const* d_in, const int* in_sizes, int n_in,
                              void* d_out, int out_size, void* d_ws, size_t ws_size,
                              hipStream_t stream)
{
    const float* u   = (const float*)d_in[0];
    const float* v   = (const float*)d_in[1];
    const float* ev  = (const float*)d_in[2];
    const int*   eiv = (const int*)d_in[3];
    const int*   eiu = (const int*)d_in[4];
    const float* gw1 = (const float*)d_in[5];   // 144 x 128
    const float* gb1 = (const float*)d_in[6];   // 128
    const float* gw2 = (const float*)d_in[7];   // 128 x 64
    const float* gb2 = (const float*)d_in[8];   // 64
    const float* fw1 = (const float*)d_in[9];   // 128 x 128
    const float* fb1 = (const float*)d_in[10];  // 128
    const float* fw2 = (const float*)d_in[11];  // 128 x 64
    const float* fb2 = (const float*)d_in[12];  // 64
    float* out = (float*)d_out;

    // workspace layout (agg and counts adjacent -> single memset); ~67.5 MB
    unsigned short* Up     = (unsigned short*)d_ws;                 // 50000x128 bf16
    unsigned short* Vp     = Up + (size_t)U_N * 128;                // 50000x128 bf16
    unsigned short* evs    = Vp + (size_t)V_N * 128;                // E x 16 bf16
    float*          agg    = (float*)(evs + (size_t)E_N * 16);      // 50000x64 f32
    int*            counts = (int*)(agg + (size_t)U_N * 64);        // NBINS (= cursor)
    unsigned int*   iuv_s  = (unsigned int*)(counts + NBINS);       // 800000
    unsigned short* W2f    = (unsigned short*)(iuv_s + E_N);        // 8192 bf16
    unsigned short* Wef    = W2f + 8192;                            // 4096 bf16
    unsigned short* F1f    = Wef + 4096;                            // 16384 bf16
    unsigned short* F2f    = F1f + 16384;                           // 8192 bf16
    int*            bsum   = (int*)(F2f + 8192);                    // NSCAN ints

    // one memset covers agg (zero init) + counts (hist init)
    hipMemsetAsync(agg, 0, ((size_t)U_N * 64 + NBINS) * sizeof(float), stream);

    dim3 blk(256);
    prep_kernel<<<dim3(2 * NB_PROJ + 1 + NB_HIST), blk, 0, stream>>>(
        eiu, counts, u, v, gw1, gw2, fw1, fw2, Up, Vp, W2f, Wef, F1f, F2f);
    scan_sums<<<dim3(NSCAN), blk, 0, stream>>>(counts, bsum);
    scan_bsum<<<dim3(1), dim3(512), 0, stream>>>(bsum);
    scan_apply<<<dim3(NSCAN), blk, 0, stream>>>(counts, bsum);
    permute_kernel<<<dim3(NB_HIST), blk, 0, stream>>>(
        eiu, eiv, ev, counts, iuv_s, evs);

    edge_kernel<<<dim3(E_N / 64), blk, 0, stream>>>(
        Up, Vp, evs, iuv_s, Wef, gb1, W2f, gb2, agg);
    node_kernel<<<dim3((U_N + 63) / 64), blk, 0, stream>>>(
        u, agg, F1f, fb1, F2f, fb2, out, U_N);
}

// Round 13
// 231.496 us; speedup vs baseline: 3.3004x; 1.1476x over previous
//
#include <hip/hip_runtime.h>

// Problem constants (match reference)
constexpr int U_N = 50000;
constexpr int V_N = 50000;
constexpr int E_N = 800000;   // == 64 * 12500
// dims: F=64, G=64, H=16; g: 144->128->64; f: 128->128->64

typedef float f32x4 __attribute__((ext_vector_type(4)));
typedef short bf16x8 __attribute__((ext_vector_type(8)));
typedef unsigned short u16x8 __attribute__((ext_vector_type(8)));

__device__ __forceinline__ float relu(float x) { return fmaxf(x, 0.f); }

// round-to-nearest-even fp32 -> bf16 bits
__device__ __forceinline__ unsigned short f2bf(float f) {
    unsigned u = __float_as_uint(f);
    unsigned rounding = 0x7FFFu + ((u >> 16) & 1u);
    return (unsigned short)((u + rounding) >> 16);
}
__device__ __forceinline__ float bf2f(unsigned short b) {
    return __uint_as_float(((unsigned)b) << 16);
}

constexpr int NB_HIST = (E_N + 255) / 256;   // 3125
constexpr int NB_PROJ = (U_N + 63) / 64;     // 782
constexpr int NBINS = U_N;                   // 50000
constexpr int NSCAN = (NBINS + 1023) / 1024; // 49

// Up/Vp rows are stored FRAGMENT-PERMUTED: element (col = ct*16 + hi*4 + j)
// lives at row offset hi*32 + ct*4 + j  (hi 0..3, ct 0..7, j 0..3).
// => each edge-kernel lane's 64B of gather data is CONTIGUOUS: 4 x 16B loads
// instead of 8 x 8B. Halves gather load-instruction count (MLP ceiling).

// ---------------------------------------------------------------------------
// proj via MFMA: P[row][*] = bf16(X[.][64]) @ bf16(W[64][128]), permuted store
// ---------------------------------------------------------------------------
__device__ __forceinline__ void proj_mfma(const float* __restrict__ X,
                                          const float* __restrict__ W,  // 64x128
                                          unsigned short* __restrict__ P,
                                          int N, int row0,
                                          unsigned short* sWf)
{
    const int tid = threadIdx.x;

    for (int idx = tid; idx < 64 * 128 / 4; idx += 256) {
        int k  = (idx * 4) >> 7;
        int n0 = (idx * 4) & 127;
        float4 w = *(const float4*)&W[k * 128 + n0];
        int ks = k >> 5, hi = (k & 31) >> 3, j = k & 7;
        float wv[4] = {w.x, w.y, w.z, w.w};
#pragma unroll
        for (int q = 0; q < 4; ++q) {
            int n = n0 + q, nt = n >> 4, lo = n & 15;
            sWf[((ks * 8 + nt) * 64 + hi * 16 + lo) * 8 + j] = f2bf(wv[q]);
        }
    }
    __syncthreads();

    const int wid = tid >> 6, lane = tid & 63;
    const int lo = lane & 15, hi = lane >> 4;
    const int row = row0 + wid * 16 + lo;
    const int rl = (row < N) ? row : (N - 1);

    bf16x8 a0, a1;
    {
        union { bf16x8 v; unsigned short s[8]; } ra, rb;
        float4 x0 = *(const float4*)&X[(size_t)rl * 64 + hi * 8];
        float4 x1 = *(const float4*)&X[(size_t)rl * 64 + hi * 8 + 4];
        ra.s[0] = f2bf(x0.x); ra.s[1] = f2bf(x0.y); ra.s[2] = f2bf(x0.z); ra.s[3] = f2bf(x0.w);
        ra.s[4] = f2bf(x1.x); ra.s[5] = f2bf(x1.y); ra.s[6] = f2bf(x1.z); ra.s[7] = f2bf(x1.w);
        float4 y0 = *(const float4*)&X[(size_t)rl * 64 + 32 + hi * 8];
        float4 y1 = *(const float4*)&X[(size_t)rl * 64 + 32 + hi * 8 + 4];
        rb.s[0] = f2bf(y0.x); rb.s[1] = f2bf(y0.y); rb.s[2] = f2bf(y0.z); rb.s[3] = f2bf(y0.w);
        rb.s[4] = f2bf(y1.x); rb.s[5] = f2bf(y1.y); rb.s[6] = f2bf(y1.z); rb.s[7] = f2bf(y1.w);
        a0 = ra.v; a1 = rb.v;
    }

    const int rbase = row0 + wid * 16 + hi * 4;
    const int ph = lo >> 2, pj = lo & 3;   // permuted-store decomposition of col
#pragma unroll
    for (int nt = 0; nt < 8; ++nt) {
        f32x4 acc;
#pragma unroll
        for (int r = 0; r < 4; ++r) acc[r] = 0.f;
        bf16x8 b0 = *(const bf16x8*)&sWf[((0 * 8 + nt) * 64 + lane) * 8];
        bf16x8 b1 = *(const bf16x8*)&sWf[((1 * 8 + nt) * 64 + lane) * 8];
        acc = __builtin_amdgcn_mfma_f32_16x16x32_bf16(a0, b0, acc, 0, 0, 0);
        acc = __builtin_amdgcn_mfma_f32_16x16x32_bf16(a1, b1, acc, 0, 0, 0);
#pragma unroll
        for (int r = 0; r < 4; ++r) {
            int gr = rbase + r;
            // col = nt*16 + lo  ->  permuted pos = (lo>>2)*32 + nt*4 + (lo&3)
            if (gr < N) P[(size_t)gr * 128 + ph * 32 + nt * 4 + pj] = f2bf(acc[r]);
        }
    }
}

// ---------------------------------------------------------------------------
// prep kernel: projU (MFMA), projV (MFMA), weight-pack, histogram.
// ---------------------------------------------------------------------------
__global__ __launch_bounds__(256) void prep_kernel(
    const int* __restrict__ idx_u, int* __restrict__ counts,
    const float* __restrict__ u, const float* __restrict__ v,
    const float* __restrict__ gw1, const float* __restrict__ gw2,
    const float* __restrict__ fw1, const float* __restrict__ fw2,
    unsigned short* __restrict__ Up, unsigned short* __restrict__ Vp,
    unsigned short* __restrict__ W2f, unsigned short* __restrict__ Wef,
    unsigned short* __restrict__ F1f, unsigned short* __restrict__ F2f)
{
    __shared__ unsigned short sWf[8192];   // proj branches only
    int b = blockIdx.x;

    if (b < NB_PROJ) {
        proj_mfma(u, gw1, Up, U_N, b * 64, sWf);
        return;
    }
    b -= NB_PROJ;
    if (b < NB_PROJ) {
        proj_mfma(v, gw1 + 64 * 128, Vp, V_N, b * 64, sWf);
        return;
    }
    b -= NB_PROJ;
    if (b == 0) {
        const int tid = threadIdx.x;
        // W2f (edge L2, gw2 128x64) and F2f (node L2, fw2 128x64): same layout
        for (int t = tid; t < 4 * 4 * 64 * 8; t += 256) {
            int j    = t & 7;
            int lane = (t >> 3) & 63;
            int nt   = (t >> 9) & 3;
            int ks   = t >> 11;
            int n = nt * 16 + (lane & 15);
            int k = ks * 32 + (lane >> 4) * 8 + j;
            W2f[t] = f2bf(gw2[k * 64 + n]);
            F2f[t] = f2bf(fw2[k * 64 + n]);
        }
        // Wef (edge L1 A-frags, We^T, K padded to 32)
        const float* gw1e = gw1 + 128 * 128;   // 16 x 128
        for (int t = tid; t < 8 * 64 * 8; t += 256) {
            int j    = t & 7;
            int lane = (t >> 3) & 63;
            int ct   = t >> 9;
            int c = ct * 16 + (lane & 15);
            int k = (lane >> 4) * 8 + j;
            Wef[t] = (k < 16) ? f2bf(gw1e[k * 128 + c]) : (unsigned short)0;
        }
        // F1f (node L1, fw1 128x128): ks 0..3, nt 0..7
        for (int t = tid; t < 4 * 8 * 64 * 8; t += 256) {
            int j    = t & 7;
            int lane = (t >> 3) & 63;
            int nt   = (t >> 9) & 7;
            int ks   = t >> 12;
            int n = nt * 16 + (lane & 15);
            int k = ks * 32 + (lane >> 4) * 8 + j;
            F1f[t] = f2bf(fw1[k * 128 + n]);
        }
        return;
    }
    b -= 1;
    // ---- histogram (key = iu) ----
    int e = b * 256 + threadIdx.x;
    if (e < E_N) atomicAdd(&counts[idx_u[e]], 1);
}

// ---------------------------------------------------------------------------
// multi-block exclusive scan of counts[0..NBINS): sums -> scan sums -> apply
// ---------------------------------------------------------------------------
__global__ __launch_bounds__(256) void scan_sums(const int* __restrict__ counts,
                                                 int* __restrict__ bsum)
{
    __shared__ int sred[256];
    const int tid = threadIdx.x;
    int base = blockIdx.x * 1024 + tid * 4;
    int s = 0;
    if (base + 3 < NBINS) {
        int4 c = *(const int4*)&counts[base];
        s = c.x + c.y + c.z + c.w;
    } else {
#pragma unroll
        for (int k = 0; k < 4; ++k) { int i = base + k; if (i < NBINS) s += counts[i]; }
    }
    sred[tid] = s;
    __syncthreads();
    for (int off = 128; off > 0; off >>= 1) {
        if (tid < off) sred[tid] += sred[tid + off];
        __syncthreads();
    }
    if (tid == 0) bsum[blockIdx.x] = sred[0];
}

__global__ __launch_bounds__(512) void scan_bsum(int* __restrict__ bsum)
{
    __shared__ int sScan[512];
    const int tid = threadIdx.x;
    int vIn = (tid < NSCAN) ? bsum[tid] : 0;
    sScan[tid] = vIn;
    __syncthreads();
    for (int off = 1; off < 512; off <<= 1) {
        int val = (tid >= off) ? sScan[tid - off] : 0;
        __syncthreads();
        sScan[tid] += val;
        __syncthreads();
    }
    if (tid < NSCAN) bsum[tid] = sScan[tid] - vIn;   // exclusive
}

__global__ __launch_bounds__(256) void scan_apply(int* __restrict__ counts,
                                                  const int* __restrict__ bsum)
{
    __shared__ int sScan[256];
    const int tid = threadIdx.x;
    int base = blockIdx.x * 1024 + tid * 4;
    int v0 = 0, v1 = 0, v2 = 0, v3 = 0;
    if (base + 3 < NBINS) {
        int4 c = *(const int4*)&counts[base];
        v0 = c.x; v1 = c.y; v2 = c.z; v3 = c.w;
    } else {
        if (base     < NBINS) v0 = counts[base];
        if (base + 1 < NBINS) v1 = counts[base + 1];
        if (base + 2 < NBINS) v2 = counts[base + 2];
        if (base + 3 < NBINS) v3 = counts[base + 3];
    }
    int tsum = v0 + v1 + v2 + v3;
    sScan[tid] = tsum;
    __syncthreads();
    for (int off = 1; off < 256; off <<= 1) {
        int val = (tid >= off) ? sScan[tid - off] : 0;
        __syncthreads();
        sScan[tid] += val;
        __syncthreads();
    }
    int excl = sScan[tid] - tsum + bsum[blockIdx.x];
    if (base     < NBINS) counts[base]     = excl;
    if (base + 1 < NBINS) counts[base + 1] = excl + v0;
    if (base + 2 < NBINS) counts[base + 2] = excl + v0 + v1;
    if (base + 3 < NBINS) counts[base + 3] = excl + v0 + v1 + v2;
}

// ---------------------------------------------------------------------------
// permute+gather: scatter edges into iu-sorted order, pre-gathering
// iuv packed indices + ev row as bf16.
// ---------------------------------------------------------------------------
__global__ __launch_bounds__(256) void permute_kernel(
    const int* __restrict__ idx_u, const int* __restrict__ idx_v,
    const float* __restrict__ ev, int* __restrict__ cursor,
    unsigned int* __restrict__ iuv_s, unsigned short* __restrict__ evs)
{
    int e = blockIdx.x * 256 + threadIdx.x;
    if (e >= E_N) return;
    int iu = idx_u[e];
    int iv = idx_v[e];
    int pos = atomicAdd(&cursor[iu], 1);
    iuv_s[pos] = (unsigned)iu | ((unsigned)iv << 16);

    const float* src = &ev[(size_t)e * 16];
    unsigned short* dst = &evs[(size_t)pos * 16];
#pragma unroll
    for (int q = 0; q < 4; ++q) {
        float4 a = *(const float4*)&src[q * 4];
        ushort4 o;
        o.x = f2bf(a.x); o.y = f2bf(a.y); o.z = f2bf(a.z); o.w = f2bf(a.w);
        *(ushort4*)&dst[q * 4] = o;
    }
}

// ---------------------------------------------------------------------------
// edge kernel over SORTED pre-gathered edges (R9 structure, spill-free
// launch_bounds(256,5)); Up/Vp rows fragment-permuted -> each lane's gather
// is 4 contiguous 16B loads per table (was 8x8B): half the load instructions
// on the latency-bound path.
// ---------------------------------------------------------------------------
__global__ __launch_bounds__(256, 5) void edge_kernel(
    const unsigned short* __restrict__ Up,   // 50000 x 128 bf16, permuted rows
    const unsigned short* __restrict__ Vp,   // 50000 x 128 bf16, permuted rows
    const unsigned short* __restrict__ evs,  // E x 16 bf16, sorted
    const unsigned int* __restrict__ iuv_s,  // E packed (iu | iv<<16), sorted
    const unsigned short* __restrict__ Wef,  // layer-1 A frags (We^T, K=32 pad)
    const float* __restrict__ gb1,
    const unsigned short* __restrict__ W2f,  // layer-2 B frags
    const float* __restrict__ gb2,
    float* __restrict__ agg)
{
    __shared__ unsigned short sH1[64 * 136];  // aliased as sH2 f32 [64][68]
    __shared__ int sIu[64];

    const int tid = threadIdx.x;
    const int e0 = blockIdx.x * 64;
    const int wid = tid >> 6, lane = tid & 63;
    const int lo = lane & 15, hi = lane >> 4;
    const int g = e0 + wid * 16 + lo;         // this lane's (sorted) edge

    const unsigned iuv = iuv_s[g];
    const int iu = (int)(iuv & 0xFFFFu);
    const int iv = (int)(iuv >> 16);
    if (hi == 0) sIu[wid * 16 + lo] = iu;     // wave-local write

    // ---- register-prefetch the gathers: 4+4 contiguous 16B loads ----
    u16x8 upv[4], vpv[4];
#pragma unroll
    for (int ctp = 0; ctp < 4; ++ctp) {
        upv[ctp] = *(const u16x8*)&Up[(size_t)iu * 128 + hi * 32 + ctp * 8];
        vpv[ctp] = *(const u16x8*)&Vp[(size_t)iv * 128 + hi * 32 + ctp * 8];
    }

    // ---- layer 1 MFMA: B-frag = evs row (coalesced); A = Wef (L1-hot) ----
    bf16x8 bfrag;
    if (hi < 2) {
        bfrag = *(const bf16x8*)&evs[(size_t)g * 16 + hi * 8];
    } else {
        bfrag = (bf16x8)(short)0;             // K-pad 16->32
    }

    f32x4 acc[8];
#pragma unroll
    for (int ct = 0; ct < 8; ++ct) {
#pragma unroll
        for (int r = 0; r < 4; ++r) acc[ct][r] = 0.f;
        bf16x8 a = *(const bf16x8*)&Wef[(size_t)((ct * 64 + lane) * 8)];
        acc[ct] = __builtin_amdgcn_mfma_f32_16x16x32_bf16(a, bfrag, acc[ct], 0, 0, 0);
    }

    // epilogue: h1 = relu(acc + b1 + Up[iu] + Vp[iv]) -> bf16 LDS (wave-local)
    // upv[ctp]/vpv[ctp] hold cts {2ctp, 2ctp+1}: elems 0-3 and 4-7.
    const int e_loc = wid * 16 + lo;
#pragma unroll
    for (int ctp = 0; ctp < 4; ++ctp) {
        u16x8 uv = upv[ctp], vv = vpv[ctp];
#pragma unroll
        for (int half = 0; half < 2; ++half) {
            const int ct = ctp * 2 + half;
            const int c0 = ct * 16 + hi * 4;
            float4 b1 = *(const float4*)&gb1[c0];
            ushort4 h;
            h.x = f2bf(relu(acc[ct][0] + b1.x + bf2f(uv[half * 4 + 0]) + bf2f(vv[half * 4 + 0])));
            h.y = f2bf(relu(acc[ct][1] + b1.y + bf2f(uv[half * 4 + 1]) + bf2f(vv[half * 4 + 1])));
            h.z = f2bf(relu(acc[ct][2] + b1.z + bf2f(uv[half * 4 + 2]) + bf2f(vv[half * 4 + 2])));
            h.w = f2bf(relu(acc[ct][3] + b1.w + bf2f(uv[half * 4 + 3]) + bf2f(vv[half * 4 + 3])));
            *(ushort4*)&sH1[e_loc * 136 + c0] = h;
        }
    }
    // intra-wave ushort write->read on same array: compiler-ordered, no barrier

    // ---- layer 2 via MFMA: wave reads its OWN 16 rows of sH1 ----
    f32x4 accm[4];
#pragma unroll
    for (int nt = 0; nt < 4; ++nt)
#pragma unroll
        for (int r = 0; r < 4; ++r) accm[nt][r] = 0.f;

#pragma unroll
    for (int ks = 0; ks < 4; ++ks) {
        bf16x8 a = *(const bf16x8*)&sH1[(wid * 16 + lo) * 136 + ks * 32 + hi * 8];
#pragma unroll
        for (int nt = 0; nt < 4; ++nt) {
            bf16x8 b = *(const bf16x8*)&W2f[(size_t)(((ks * 4 + nt) * 64 + lane) * 8)];
            accm[nt] = __builtin_amdgcn_mfma_f32_16x16x32_bf16(a, b, accm[nt], 0, 0, 0);
        }
    }
    __syncthreads();   // alias (ushort->float) boundary: all sH1 reads done

    float* sH2 = (float*)sH1;   // [64][68] fp32; wave-local byte range coincides
#pragma unroll
    for (int nt = 0; nt < 4; ++nt) {
        int col = nt * 16 + lo;
        float b2v = gb2[col];
        int erow = wid * 16 + hi * 4;
#pragma unroll
        for (int r = 0; r < 4; ++r)
            sH2[(erow + r) * 68 + col] = relu(accm[nt][r] + b2v);
    }
    // reduction reads own wave's rows (float->float, intra-wave): no barrier

    // ---- segmented reduction over sorted iu: thread = (col, own wave) ----
    {
        const int c = tid & 63;       // output column
        const int eq0 = wid * 16;     // this wave's 16 edges
        int   iu_cur = sIu[eq0];
        float running = 0.f;
#pragma unroll
        for (int k = 0; k < 16; ++k) {
            int e = eq0 + k;
            int iu2 = sIu[e];
            if (iu2 != iu_cur) {
                atomicAdd(&agg[(size_t)iu_cur * 64 + c], running);
                running = 0.f;
                iu_cur = iu2;
            }
            running += sH2[e * 68 + c];
        }
        atomicAdd(&agg[(size_t)iu_cur * 64 + c], running);
    }
}

// ---------------------------------------------------------------------------
// node kernel via MFMA: out = relu(relu([u,agg] @ fw1 + fb1) @ fw2 + fb2)
// (reads u/agg directly; unaffected by the Up/Vp permutation)
// ---------------------------------------------------------------------------
__global__ __launch_bounds__(256) void node_kernel(
    const float* __restrict__ u, const float* __restrict__ agg,
    const unsigned short* __restrict__ F1f, const float* __restrict__ fb1,
    const unsigned short* __restrict__ F2f, const float* __restrict__ fb2,
    float* __restrict__ out, int N)
{
    __shared__ unsigned short sY[64 * 136];   // y bf16, wave-local rows
    const int tid = threadIdx.x;
    const int wid = tid >> 6, lane = tid & 63;
    const int lo = lane & 15, hi = lane >> 4;
    const int row0 = blockIdx.x * 64;
    const int row = row0 + wid * 16 + lo;
    const int rl = (row < N) ? row : (N - 1);

    bf16x8 a0, a1, a2, a3;
    {
        union { bf16x8 v; unsigned short s[8]; } r0_, r1_, r2_, r3_;
        float4 x0 = *(const float4*)&u[(size_t)rl * 64 + hi * 8];
        float4 x1 = *(const float4*)&u[(size_t)rl * 64 + hi * 8 + 4];
        float4 x2 = *(const float4*)&u[(size_t)rl * 64 + 32 + hi * 8];
        float4 x3 = *(const float4*)&u[(size_t)rl * 64 + 32 + hi * 8 + 4];
        float4 g0 = *(const float4*)&agg[(size_t)rl * 64 + hi * 8];
        float4 g1 = *(const float4*)&agg[(size_t)rl * 64 + hi * 8 + 4];
        float4 g2 = *(const float4*)&agg[(size_t)rl * 64 + 32 + hi * 8];
        float4 g3 = *(const float4*)&agg[(size_t)rl * 64 + 32 + hi * 8 + 4];
        r0_.s[0] = f2bf(x0.x); r0_.s[1] = f2bf(x0.y); r0_.s[2] = f2bf(x0.z); r0_.s[3] = f2bf(x0.w);
        r0_.s[4] = f2bf(x1.x); r0_.s[5] = f2bf(x1.y); r0_.s[6] = f2bf(x1.z); r0_.s[7] = f2bf(x1.w);
        r1_.s[0] = f2bf(x2.x); r1_.s[1] = f2bf(x2.y); r1_.s[2] = f2bf(x2.z); r1_.s[3] = f2bf(x2.w);
        r1_.s[4] = f2bf(x3.x); r1_.s[5] = f2bf(x3.y); r1_.s[6] = f2bf(x3.z); r1_.s[7] = f2bf(x3.w);
        r2_.s[0] = f2bf(g0.x); r2_.s[1] = f2bf(g0.y); r2_.s[2] = f2bf(g0.z); r2_.s[3] = f2bf(g0.w);
        r2_.s[4] = f2bf(g1.x); r2_.s[5] = f2bf(g1.y); r2_.s[6] = f2bf(g1.z); r2_.s[7] = f2bf(g1.w);
        r3_.s[0] = f2bf(g2.x); r3_.s[1] = f2bf(g2.y); r3_.s[2] = f2bf(g2.z); r3_.s[3] = f2bf(g2.w);
        r3_.s[4] = f2bf(g3.x); r3_.s[5] = f2bf(g3.y); r3_.s[6] = f2bf(g3.z); r3_.s[7] = f2bf(g3.w);
        a0 = r0_.v; a1 = r1_.v; a2 = r2_.v; a3 = r3_.v;
    }

    // ---- layer 1: y = relu(x @ fw1 + fb1), 32 MFMAs/wave ----
#pragma unroll
    for (int nt = 0; nt < 8; ++nt) {
        f32x4 acc;
#pragma unroll
        for (int r = 0; r < 4; ++r) acc[r] = 0.f;
        bf16x8 b0 = *(const bf16x8*)&F1f[(size_t)(((0 * 8 + nt) * 64 + lane) * 8)];
        bf16x8 b1 = *(const bf16x8*)&F1f[(size_t)(((1 * 8 + nt) * 64 + lane) * 8)];
        bf16x8 b2 = *(const bf16x8*)&F1f[(size_t)(((2 * 8 + nt) * 64 + lane) * 8)];
        bf16x8 b3 = *(const bf16x8*)&F1f[(size_t)(((3 * 8 + nt) * 64 + lane) * 8)];
        acc = __builtin_amdgcn_mfma_f32_16x16x32_bf16(a0, b0, acc, 0, 0, 0);
        acc = __builtin_amdgcn_mfma_f32_16x16x32_bf16(a1, b1, acc, 0, 0, 0);
        acc = __builtin_amdgcn_mfma_f32_16x16x32_bf16(a2, b2, acc, 0, 0, 0);
        acc = __builtin_amdgcn_mfma_f32_16x16x32_bf16(a3, b3, acc, 0, 0, 0);
        int col = nt * 16 + lo;
        float b1v = fb1[col];
        int rbase = wid * 16 + hi * 4;
#pragma unroll
        for (int r = 0; r < 4; ++r)
            sY[(rbase + r) * 136 + col] = f2bf(relu(acc[r] + b1v));
    }

    // ---- layer 2: out = relu(y @ fw2 + fb2), 16 MFMAs/wave ----
    bf16x8 ya0 = *(const bf16x8*)&sY[(wid * 16 + lo) * 136 + 0 * 32 + hi * 8];
    bf16x8 ya1 = *(const bf16x8*)&sY[(wid * 16 + lo) * 136 + 1 * 32 + hi * 8];
    bf16x8 ya2 = *(const bf16x8*)&sY[(wid * 16 + lo) * 136 + 2 * 32 + hi * 8];
    bf16x8 ya3 = *(const bf16x8*)&sY[(wid * 16 + lo) * 136 + 3 * 32 + hi * 8];
#pragma unroll
    for (int nt = 0; nt < 4; ++nt) {
        f32x4 acc;
#pragma unroll
        for (int r = 0; r < 4; ++r) acc[r] = 0.f;
        bf16x8 b0 = *(const bf16x8*)&F2f[(size_t)(((0 * 4 + nt) * 64 + lane) * 8)];
        bf16x8 b1 = *(const bf16x8*)&F2f[(size_t)(((1 * 4 + nt) * 64 + lane) * 8)];
        bf16x8 b2 = *(const bf16x8*)&F2f[(size_t)(((2 * 4 + nt) * 64 + lane) * 8)];
        bf16x8 b3 = *(const bf16x8*)&F2f[(size_t)(((3 * 4 + nt) * 64 + lane) * 8)];
        acc = __builtin_amdgcn_mfma_f32_16x16x32_bf16(ya0, b0, acc, 0, 0, 0);
        acc = __builtin_amdgcn_mfma_f32_16x16x32_bf16(ya1, b1, acc, 0, 0, 0);
        acc = __builtin_amdgcn_mfma_f32_16x16x32_bf16(ya2, b2, acc, 0, 0, 0);
        acc = __builtin_amdgcn_mfma_f32_16x16x32_bf16(ya3, b3, acc, 0, 0, 0);
        int col = nt * 16 + lo;
        float b2v = fb2[col];
#pragma unroll
        for (int r = 0; r < 4; ++r) {
            int gr = row0 + wid * 16 + hi * 4 + r;
            if (gr < N) out[(size_t)gr * 64 + col] = relu(acc[r] + b2v);
        }
    }
}

// ---------------------------------------------------------------------------
extern "C" void kernel_launch(void* const* d_in, const int* in_sizes, int n_in,
                              void* d_out, int out_size, void* d_ws, size_t ws_size,
                              hipStream_t stream)
{
    const float* u   = (const float*)d_in[0];
    const float* v   = (const float*)d_in[1];
    const float* ev  = (const float*)d_in[2];
    const int*   eiv = (const int*)d_in[3];
    const int*   eiu = (const int*)d_in[4];
    const float* gw1 = (const float*)d_in[5];   // 144 x 128
    const float* gb1 = (const float*)d_in[6];   // 128
    const float* gw2 = (const float*)d_in[7];   // 128 x 64
    const float* gb2 = (const float*)d_in[8];   // 64
    const float* fw1 = (const float*)d_in[9];   // 128 x 128
    const float* fb1 = (const float*)d_in[10];  // 128
    const float* fw2 = (const float*)d_in[11];  // 128 x 64
    const float* fb2 = (const float*)d_in[12];  // 64
    float* out = (float*)d_out;

    // workspace layout (agg and counts adjacent -> single memset); ~67.5 MB
    unsigned short* Up     = (unsigned short*)d_ws;                 // 50000x128 bf16
    unsigned short* Vp     = Up + (size_t)U_N * 128;                // 50000x128 bf16
    unsigned short* evs    = Vp + (size_t)V_N * 128;                // E x 16 bf16
    float*          agg    = (float*)(evs + (size_t)E_N * 16);      // 50000x64 f32
    int*            counts = (int*)(agg + (size_t)U_N * 64);        // NBINS (= cursor)
    unsigned int*   iuv_s  = (unsigned int*)(counts + NBINS);       // 800000
    unsigned short* W2f    = (unsigned short*)(iuv_s + E_N);        // 8192 bf16
    unsigned short* Wef    = W2f + 8192;                            // 4096 bf16
    unsigned short* F1f    = Wef + 4096;                            // 16384 bf16
    unsigned short* F2f    = F1f + 16384;                           // 8192 bf16
    int*            bsum   = (int*)(F2f + 8192);                    // NSCAN ints

    // one memset covers agg (zero init) + counts (hist init)
    hipMemsetAsync(agg, 0, ((size_t)U_N * 64 + NBINS) * sizeof(float), stream);

    dim3 blk(256);
    prep_kernel<<<dim3(2 * NB_PROJ + 1 + NB_HIST), blk, 0, stream>>>(
        eiu, counts, u, v, gw1, gw2, fw1, fw2, Up, Vp, W2f, Wef, F1f, F2f);
    scan_sums<<<dim3(NSCAN), blk, 0, stream>>>(counts, bsum);
    scan_bsum<<<dim3(1), dim3(512), 0, stream>>>(bsum);
    scan_apply<<<dim3(NSCAN), blk, 0, stream>>>(counts, bsum);
    permute_kernel<<<dim3(NB_HIST), blk, 0, stream>>>(
        eiu, eiv, ev, counts, iuv_s, evs);

    edge_kernel<<<dim3(E_N / 64), blk, 0, stream>>>(
        Up, Vp, evs, iuv_s, Wef, gb1, W2f, gb2, agg);
    node_kernel<<<dim3((U_N + 63) / 64), blk, 0, stream>>>(
        u, agg, F1f, fb1, F2f, fb2, out, U_N);
}